// Round 6
// baseline (1566.311 us; speedup 1.0000x reference)
//
#include <hip/hip_runtime.h>

// ComplexMultiheadAttention: B=8,S=1024,F=512,E=512,H=8,C=64
// Round 6: OUT-SIZE BRANCH round. r2-r5 aborted identically; r5's clamps
// falsified "bad index arithmetic", leaving exactly one unvalidated size:
// out_size (never checked; complex64 output convention ambiguous).
//   out_size == 142,606,336 -> complex-interleaved floats (ST=2, 570 MB)
//   out_size ==  71,303,168 -> real-cast floats          (ST=1, 285 MB)
//   anything else           -> write out[0]=(float)out_size, skip work
// All attn/out addressing templated on stride ST; clamps bound every
// d_out write by the selected branch's float count (provably <= out_size).

namespace {
constexpr int Bn = 8, Sn = 1024, Fn = 512, En = 512, Hn = 8, Cn = 64;
constexpr int Mn = Bn * Sn;                       // 8192
constexpr int Qszi = Bn * Hn * Sn * Cn;           // 4,194,304 per plane
constexpr size_t Qsz = (size_t)Qszi;
constexpr int XLIM = Bn * Sn * Fn;                // floats per x plane
constexpr int WLIM = En * Fn;                     // floats per weight plane
constexpr size_t OUT1 = (size_t)Bn * Sn * Fn;     // complex elems in out   (4,194,304)
constexpr size_t ATT1 = (size_t)Bn * Hn * Sn * Sn;// complex elems in attn (67,108,864)
constexpr float RDIV = 0.08838834764831845f;      // 1/sqrt(2*C) = 1/sqrt(128)
}

__device__ __forceinline__ size_t cmin(size_t i, size_t lim) { return i < lim ? i : lim; }

__device__ __forceinline__ float bf2f(unsigned short u) {
    union { unsigned int u32; float f; } c; c.u32 = (unsigned int)u << 16; return c.f;
}
__device__ __forceinline__ unsigned short f2bf(float f) {
    union { float f; unsigned int u; } c; c.f = f;
    unsigned int r = (c.u + 0x7FFFu + ((c.u >> 16) & 1u)) >> 16;  // RNE
    return (unsigned short)r;
}

__device__ __forceinline__ float4 ld4(const float* p) { return *(const float4*)p; }
__device__ __forceinline__ float4 ld4(const unsigned short* p) {
    ushort4 v = *(const ushort4*)p;  // 8 B load
    return make_float4(bf2f(v.x), bf2f(v.y), bf2f(v.z), bf2f(v.w));
}

// 64x64-tile complex "NT" GEMM with whole-plane clamped loads.
template<bool CONJB, int LIMA, int LIMB, class TA, class TB>
__device__ __forceinline__ void cgemm64(
    const TA* __restrict__ Ar, const TA* __restrict__ Ai, int arow0, int lda,
    const TB* __restrict__ Br, const TB* __restrict__ Bi, int brow0, int ldb,
    int K, float accr[4][4], float acci[4][4])
{
    __shared__ float Asr[16][65], Asi[16][65], Bsr[16][65], Bsi[16][65];
    const int tid = threadIdx.x;
    const int tx = tid & 15, ty = tid >> 4;
    const int lr = tid >> 2, lk = (tid & 3) * 4;

    for (int k0 = 0; k0 < K; k0 += 16) {
        const size_t aidx = cmin((size_t)(arow0 + lr) * lda + k0 + lk, (size_t)(LIMA - 4));
        const size_t bidx = cmin((size_t)(brow0 + lr) * ldb + k0 + lk, (size_t)(LIMB - 4));
        float4 a4r = ld4(Ar + aidx);
        float4 a4i = ld4(Ai + aidx);
        float4 b4r = ld4(Br + bidx);
        float4 b4i = ld4(Bi + bidx);
        __syncthreads();  // prior-iteration readers done before overwrite
        Asr[lk+0][lr] = a4r.x; Asr[lk+1][lr] = a4r.y; Asr[lk+2][lr] = a4r.z; Asr[lk+3][lr] = a4r.w;
        Asi[lk+0][lr] = a4i.x; Asi[lk+1][lr] = a4i.y; Asi[lk+2][lr] = a4i.z; Asi[lk+3][lr] = a4i.w;
        Bsr[lk+0][lr] = b4r.x; Bsr[lk+1][lr] = b4r.y; Bsr[lk+2][lr] = b4r.z; Bsr[lk+3][lr] = b4r.w;
        Bsi[lk+0][lr] = b4i.x; Bsi[lk+1][lr] = b4i.y; Bsi[lk+2][lr] = b4i.z; Bsi[lk+3][lr] = b4i.w;
        __syncthreads();
        #pragma unroll
        for (int kk = 0; kk < 16; ++kk) {
            float ar[4], ai[4], br_[4], bi_[4];
            #pragma unroll
            for (int i = 0; i < 4; ++i) { ar[i] = Asr[kk][ty + 16*i]; ai[i] = Asi[kk][ty + 16*i]; }
            #pragma unroll
            for (int j = 0; j < 4; ++j) { br_[j] = Bsr[kk][tx + 16*j]; bi_[j] = Bsi[kk][tx + 16*j]; }
            #pragma unroll
            for (int i = 0; i < 4; ++i)
                #pragma unroll
                for (int j = 0; j < 4; ++j) {
                    if (CONJB) {
                        accr[i][j] = fmaf(ar[i], br_[j], fmaf( ai[i], bi_[j], accr[i][j]));
                        acci[i][j] = fmaf(ai[i], br_[j], fmaf(-ar[i], bi_[j], acci[i][j]));
                    } else {
                        accr[i][j] = fmaf(ar[i], br_[j], fmaf(-ai[i], bi_[j], accr[i][j]));
                        acci[i][j] = fmaf(ar[i], bi_[j], fmaf( ai[i], br_[j], acci[i][j]));
                    }
                }
        }
    }
}

// ---- diagnostic: write a single readable value into out[0] ----
__global__ void diag_k(float* __restrict__ out, float v) { out[0] = v; }

// ---- K1: QKV projection -> bf16 planes. grid (M/64, E/64, 3) ----
__global__ __launch_bounds__(256) void qkv_proj_k(
    const float* __restrict__ xr, const float* __restrict__ xi,
    const float* __restrict__ wqr, const float* __restrict__ wqi,
    const float* __restrict__ bqr, const float* __restrict__ bqi,
    const float* __restrict__ wkr, const float* __restrict__ wki,
    const float* __restrict__ bkr, const float* __restrict__ bki,
    const float* __restrict__ wvr, const float* __restrict__ wvi,
    const float* __restrict__ bvr, const float* __restrict__ bvi,
    unsigned short* __restrict__ ws)
{
    const int which = blockIdx.z;
    const float* wr = which == 0 ? wqr : which == 1 ? wkr : wvr;
    const float* wi = which == 0 ? wqi : which == 1 ? wki : wvi;
    const float* br = which == 0 ? bqr : which == 1 ? bkr : bvr;
    const float* bi = which == 0 ? bqi : which == 1 ? bki : bvi;
    unsigned short* outr = ws + (size_t)which * 2 * Qsz;
    unsigned short* outi = outr + Qsz;

    const int m0 = blockIdx.x * 64, n0 = blockIdx.y * 64;
    float accr[4][4] = {}, acci[4][4] = {};
    cgemm64<false, XLIM, WLIM>(xr, xi, m0, Fn, wr, wi, n0, Fn, Fn, accr, acci);

    const int tx = threadIdx.x & 15, ty = threadIdx.x >> 4;
    #pragma unroll
    for (int i = 0; i < 4; ++i) {
        const int m = m0 + ty + 16*i;
        const int b = m >> 10, s = m & (Sn - 1);
        #pragma unroll
        for (int j = 0; j < 4; ++j) {
            const int e = cmin(n0 + tx + 16*j, En - 1);
            const int h = e >> 6, c = e & (Cn - 1);
            const size_t idx = cmin((((size_t)(b * Hn + h)) * Sn + s) * Cn + c, Qsz - 1);
            outr[idx] = f2bf(accr[i][j] + br[e]);
            outi[idx] = f2bf(acci[i][j] + bi[e]);
        }
    }
}

// ---- K2: |q.conj(k)|/sqrt(2C) -> attn slot (stride ST). grid (S/64,S/64,64) ----
template<int ST>
__global__ __launch_bounds__(256) void score_k(
    const unsigned short* __restrict__ qkv, float* __restrict__ attn)
{
    const int bh = blockIdx.z;
    const int r0 = blockIdx.x * 64, t0 = blockIdx.y * 64;
    const int row0 = bh * Sn;

    float accr[4][4] = {}, acci[4][4] = {};
    cgemm64<true, Qszi, Qszi>(qkv, qkv + Qsz, row0 + r0, Cn,
                              qkv + 2 * Qsz, qkv + 3 * Qsz, row0 + t0, Cn,
                              Cn, accr, acci);

    const size_t ATTF = ATT1 * ST;
    const int tx = threadIdx.x & 15, ty = threadIdx.x >> 4;
    #pragma unroll
    for (int i = 0; i < 4; ++i) {
        const size_t row = (size_t)bh * Sn + r0 + ty + 16*i;
        #pragma unroll
        for (int j = 0; j < 4; ++j) {
            const int t = t0 + tx + 16*j;
            const float mag = sqrtf(fmaf(accr[i][j], accr[i][j], acci[i][j]*acci[i][j])) * RDIV;
            const size_t idx = cmin((row * Sn + t) * (size_t)ST, ATTF - ST);
            if (ST == 2) *(float2*)&attn[idx] = make_float2(mag, 0.f);
            else         attn[idx] = mag;
        }
    }
}

// ---- K3: in-place row softmax (stride ST). grid (S/4, 64), 1 wave/row ----
template<int ST>
__global__ __launch_bounds__(256) void softmax_k(float* __restrict__ attn)
{
    const int bh = blockIdx.y;
    const int wid = threadIdx.x >> 6, lane = threadIdx.x & 63;
    const int row = blockIdx.x * 4 + wid;
    const size_t rbase = ((size_t)bh * Sn + row) * Sn;
    const size_t ATTF = ATT1 * ST;

    float v[16];
    float mx = -1e30f;
    #pragma unroll
    for (int j = 0; j < 16; ++j) {
        v[j] = attn[cmin((rbase + lane + 64*j) * (size_t)ST, ATTF - ST)];
        mx = fmaxf(mx, v[j]);
    }
    #pragma unroll
    for (int m = 32; m >= 1; m >>= 1) mx = fmaxf(mx, __shfl_xor(mx, m));
    float sum = 0.f;
    #pragma unroll
    for (int j = 0; j < 16; ++j) { v[j] = __expf(v[j] - mx); sum += v[j]; }
    #pragma unroll
    for (int m = 32; m >= 1; m >>= 1) sum += __shfl_xor(sum, m);
    const float inv = 1.f / sum;
    #pragma unroll
    for (int j = 0; j < 16; ++j)
        attn[cmin((rbase + lane + 64*j) * (size_t)ST, ATTF - ST)] = v[j] * inv;
}

// ---- K4: av = attn @ conj(v) (attn stride ST) -> fp32 planes. grid (S/32, 64) ----
template<int ST>
__global__ __launch_bounds__(256) void av_k(
    const unsigned short* __restrict__ qkv, const float* __restrict__ attn,
    float* __restrict__ av)
{
    const int bh = blockIdx.y;
    const int r0 = blockIdx.x * 32;
    const size_t off = (size_t)bh * Sn * Cn;
    const unsigned short* vr = qkv + 4 * Qsz;
    const unsigned short* vi = qkv + 5 * Qsz;
    const size_t abase = ((size_t)bh * Sn + r0) * Sn;
    const size_t ATTF = ATT1 * ST;

    __shared__ float ps[32][64];                // 8 KB (P tile)
    __shared__ float vsr[64][64], vsi[64][64];  // 16 KB each (V tile)

    const int tid = threadIdx.x;
    const int rg = tid >> 5;      // 0..7 -> rows rg*4+i
    const int cp = tid & 31;      // columns 2*cp, 2*cp+1
    const int pr = tid >> 3;      // P stage row 0..31
    const int pt = (tid & 7) * 8; // P stage t base
    const int st = tid >> 4;      // V stage t 0..15 (+16*rep)
    const int sc0 = (tid & 15) * 4;

    float ar_[4][2] = {}, ai_[4][2] = {};

    for (int tt = 0; tt < Sn; tt += 64) {
        __syncthreads();
        #pragma unroll
        for (int j = 0; j < 8; ++j)
            ps[pr][pt + j] = attn[cmin((abase + (size_t)pr * Sn + tt + pt + j) * (size_t)ST, ATTF - ST)];
        #pragma unroll
        for (int rep = 0; rep < 4; ++rep) {
            const int t = st + rep * 16;
            const size_t vidx = cmin(off + (size_t)(tt + t) * Cn + sc0, Qsz - 4);
            *(float4*)&vsr[t][sc0] = ld4(vr + vidx);
            *(float4*)&vsi[t][sc0] = ld4(vi + vidx);
        }
        __syncthreads();
        #pragma unroll 4
        for (int t = 0; t < 64; ++t) {
            const float2 v_r = *(const float2*)&vsr[t][2*cp];
            const float2 v_i = *(const float2*)&vsi[t][2*cp];
            #pragma unroll
            for (int i = 0; i < 4; ++i) {
                const float p = ps[rg*4 + i][t];
                ar_[i][0] = fmaf(p, v_r.x, ar_[i][0]);
                ar_[i][1] = fmaf(p, v_r.y, ar_[i][1]);
                ai_[i][0] = fmaf(p, v_i.x, ai_[i][0]);
                ai_[i][1] = fmaf(p, v_i.y, ai_[i][1]);
            }
        }
    }
    const int b = bh >> 3, h = bh & 7;
    #pragma unroll
    for (int i = 0; i < 4; ++i) {
        const int srow = r0 + rg*4 + i;
        const size_t base = cmin(((size_t)(b * Sn + srow)) * En + h * Cn + 2*cp, Qsz - 2);
        *(float2*)&av[base]       = make_float2( ar_[i][0],  ar_[i][1]);
        *(float2*)&av[Qsz + base] = make_float2(-ai_[i][0], -ai_[i][1]);  // conj(v)
    }
}

// ---- K5: out = av x wo^T + bo (out stride ST). grid (M/64, F/64) ----
template<int ST>
__global__ __launch_bounds__(256) void out_proj_k(
    const float* __restrict__ avr, const float* __restrict__ avi,
    const float* __restrict__ wor, const float* __restrict__ woi,
    const float* __restrict__ bor, const float* __restrict__ boi,
    float* __restrict__ out)
{
    const int m0 = blockIdx.x * 64, n0 = blockIdx.y * 64;
    float accr[4][4] = {}, acci[4][4] = {};
    cgemm64<false, Qszi, WLIM>(avr, avi, m0, En, wor, woi, n0, En, En, accr, acci);
    const size_t OUTF = OUT1 * ST;
    const int tx = threadIdx.x & 15, ty = threadIdx.x >> 4;
    #pragma unroll
    for (int i = 0; i < 4; ++i) {
        const int m = m0 + ty + 16*i;
        #pragma unroll
        for (int j = 0; j < 4; ++j) {
            const int f = cmin(n0 + tx + 16*j, Fn - 1);
            const size_t idx = cmin(((size_t)m * Fn + f) * (size_t)ST, OUTF - ST);
            if (ST == 2)
                *(float2*)&out[idx] = make_float2(accr[i][j] + bor[f], acci[i][j] + boi[f]);
            else
                out[idx] = accr[i][j] + bor[f];
        }
    }
}

template<int ST>
static void launch_all(const float* xr, const float* xi,
                       const float* wqr, const float* wqi, const float* bqr, const float* bqi,
                       const float* wkr, const float* wki, const float* bkr, const float* bki,
                       const float* wvr, const float* wvi, const float* bvr, const float* bvi,
                       const float* wor, const float* woi, const float* bor, const float* boi,
                       unsigned short* qkv, float* av, float* out, hipStream_t stream)
{
    float* attn = out + OUT1 * ST;
    qkv_proj_k<<<dim3(Mn/64, En/64, 3), 256, 0, stream>>>(
        xr, xi, wqr, wqi, bqr, bqi, wkr, wki, bkr, bki, wvr, wvi, bvr, bvi, qkv);
    score_k<ST><<<dim3(Sn/64, Sn/64, Bn*Hn), 256, 0, stream>>>(qkv, attn);
    softmax_k<ST><<<dim3(Sn/4, Bn*Hn), 256, 0, stream>>>(attn);
    av_k<ST><<<dim3(Sn/32, Bn*Hn), 256, 0, stream>>>(qkv, attn, av);
    out_proj_k<ST><<<dim3(Mn/64, Fn/64), 256, 0, stream>>>(
        av, av + Qsz, wor, woi, bor, boi, out);
}

extern "C" void kernel_launch(void* const* d_in, const int* in_sizes, int n_in,
                              void* d_out, int out_size, void* d_ws, size_t ws_size,
                              hipStream_t stream)
{
    // ---- host-side guards ----
    bool sizes_ok = (n_in == 18);
    if (sizes_ok) {
        sizes_ok = in_sizes[0] == XLIM && in_sizes[1] == XLIM;
        for (int g = 0; g < 3 && sizes_ok; ++g) {
            sizes_ok = in_sizes[2 + 4*g] == WLIM && in_sizes[3 + 4*g] == WLIM &&
                       in_sizes[4 + 4*g] == En  && in_sizes[5 + 4*g] == En;
        }
        sizes_ok = sizes_ok && in_sizes[14] == WLIM && in_sizes[15] == WLIM &&
                   in_sizes[16] == Fn && in_sizes[17] == Fn;
    }
    const size_t ws_needed = 6 * Qsz * sizeof(unsigned short);  // 48 MiB
    const bool ws_ok = (d_ws != nullptr) && (ws_size >= ws_needed);

    const long long fullF = 2LL * (long long)(OUT1 + ATT1);  // 142,606,336 floats
    const long long realF = (long long)(OUT1 + ATT1);        //  71,303,168 floats
    const int st = ((long long)out_size == fullF) ? 2
                 : ((long long)out_size == realF) ? 1 : 0;

    if (!sizes_ok || !ws_ok || st == 0) {
        // Encode the finding in out[0]; absmax report is the channel.
        float diag = !sizes_ok ? 3.0e9f
                   : !ws_ok    ? (float)(double)ws_size
                               : (float)out_size;
        diag_k<<<1, 1, 0, stream>>>((float*)d_out, diag);
        return;
    }

    const float* xr  = (const float*)d_in[0];
    const float* xi  = (const float*)d_in[1];
    const float* wqr = (const float*)d_in[2];
    const float* wqi = (const float*)d_in[3];
    const float* bqr = (const float*)d_in[4];
    const float* bqi = (const float*)d_in[5];
    const float* wkr = (const float*)d_in[6];
    const float* wki = (const float*)d_in[7];
    const float* bkr = (const float*)d_in[8];
    const float* bki = (const float*)d_in[9];
    const float* wvr = (const float*)d_in[10];
    const float* wvi = (const float*)d_in[11];
    const float* bvr = (const float*)d_in[12];
    const float* bvi = (const float*)d_in[13];
    const float* wor = (const float*)d_in[14];
    const float* woi = (const float*)d_in[15];
    const float* bor = (const float*)d_in[16];
    const float* boi = (const float*)d_in[17];

    // ws: 6 bf16 planes of Qsz (q_r,q_i,k_r,k_i,v_r,v_i) = 48 MiB.
    // After score_k, q+k planes are dead; av fp32 (2*Qsz floats = 32 MiB) overlays them.
    unsigned short* qkv = (unsigned short*)d_ws;
    float* av = (float*)d_ws;
    float* out = (float*)d_out;

    if (st == 2)
        launch_all<2>(xr, xi, wqr, wqi, bqr, bqi, wkr, wki, bkr, bki,
                      wvr, wvi, bvr, bvi, wor, woi, bor, boi, qkv, av, out, stream);
    else
        launch_all<1>(xr, xi, wqr, wqi, bqr, bqi, wkr, wki, bkr, bki,
                      wvr, wvi, bvr, bvi, wor, woi, bor, boi, qkv, av, out, stream);
}

// Round 7
// 913.918 us; speedup vs baseline: 1.7138x; 1.7138x over previous
//
#include <hip/hip_runtime.h>

// ComplexMultiheadAttention: B=8,S=1024,F=512,E=512,H=8,C=64
// Round 7: first MFMA round. r6 PASSED (1566 us) and profiled: qkv_proj_k
// ~650 us, MfmaUtil=0, VALUBusy=77% -> fp32-VALU-bound GEMM. This round
// converts qkv_proj and out_proj to bf16 MFMA (mfma_f32_16x16x32_bf16) via a
// shared complex-NT-GEMM template (128x64 tile, 4 waves, BK=32, fp32->bf16
// convert during LDS staging). score/softmax/av unchanged (next rounds).
//   complex via 4 real MFMAs: acc_r = ar*br -/+ ai*bi, acc_i = ar*bi +/- ai*br
//   (sign-flipped copy of one A fragment; XOR 0x80008000 on packed bf16)

namespace {
constexpr int Bn = 8, Sn = 1024, Fn = 512, En = 512, Hn = 8, Cn = 64;
constexpr int Mn = Bn * Sn;                       // 8192
constexpr int Qszi = Bn * Hn * Sn * Cn;           // 4,194,304 per plane
constexpr size_t Qsz = (size_t)Qszi;
constexpr int XLIM = Bn * Sn * Fn;                // floats per x plane
constexpr int WLIM = En * Fn;                     // floats per weight plane
constexpr size_t OUT1 = (size_t)Bn * Sn * Fn;     // complex elems in out   (4,194,304)
constexpr size_t ATT1 = (size_t)Bn * Hn * Sn * Sn;// complex elems in attn (67,108,864)
constexpr float RDIV = 0.08838834764831845f;      // 1/sqrt(2*C) = 1/sqrt(128)
}

typedef __attribute__((ext_vector_type(8))) short short8v;  // 8 bf16 (4 VGPRs)
typedef __attribute__((ext_vector_type(4))) float f32x4;

__device__ __forceinline__ size_t cmin(size_t i, size_t lim) { return i < lim ? i : lim; }

__device__ __forceinline__ float bf2f(unsigned short u) {
    union { unsigned int u32; float f; } c; c.u32 = (unsigned int)u << 16; return c.f;
}
__device__ __forceinline__ unsigned short f2bf(float f) {
    union { float f; unsigned int u; } c; c.f = f;
    unsigned int r = (c.u + 0x7FFFu + ((c.u >> 16) & 1u)) >> 16;  // RNE
    return (unsigned short)r;
}
__device__ __forceinline__ unsigned int packbf(float lo, float hi) {
    return (unsigned int)f2bf(lo) | ((unsigned int)f2bf(hi) << 16);
}
__device__ __forceinline__ short8v neg8(short8v v) {
    union { short8v s; unsigned int u[4]; } c; c.s = v;
    #pragma unroll
    for (int j = 0; j < 4; ++j) c.u[j] ^= 0x80008000u;
    return c.s;
}

__device__ __forceinline__ float4 ld4(const float* p) { return *(const float4*)p; }
__device__ __forceinline__ float4 ld4(const unsigned short* p) {
    ushort4 v = *(const ushort4*)p;  // 8 B load
    return make_float4(bf2f(v.x), bf2f(v.y), bf2f(v.z), bf2f(v.w));
}

// ================= MFMA complex NT GEMM =================
// 128x64 output tile, 256 threads = 4 waves (2x2). BK=32.
// acc[m][n] = sum_k A[arow0+m][k] * B~[brow0+n][k]; B~=conj(B) if CONJB.
// A,B are fp32 planar (r,i), K-contiguous rows (lda/ldb). Converted to bf16
// during LDS staging. Per wave: 64x32 out = 4x2 fragments of 16x16.
// Fragment layouts (gfx950 16x16x32): A/B lane reads 8 contiguous k at
// [row=lane&15][k=(lane>>4)*8]; C/D: col=lane&15, row=(lane>>4)*4+reg.
template<bool CONJB>
__device__ __forceinline__ void cgemm_mfma(
    const float* __restrict__ Ar, const float* __restrict__ Ai, int arow0, int lda,
    const float* __restrict__ Br, const float* __restrict__ Bi, int brow0, int ldb,
    int K, f32x4 accr[4][2], f32x4 acci[4][2])
{
    __shared__ short As_r[128][40], As_i[128][40];  // pad 32->40: 2-way bank alias (free)
    __shared__ short Bs_r[64][40],  Bs_i[64][40];   // total 30 KB LDS
    const int tid = threadIdx.x;
    const int sar = tid >> 1, sac = (tid & 1) * 16;  // A stage: 2 thr/row, 16 cols
    const int sbr = tid >> 2, sbc = (tid & 3) * 8;   // B stage: 4 thr/row, 8 cols
    const int wid = tid >> 6, lane = tid & 63;
    const int wr = wid >> 1, wn = wid & 1;
    const int lrow = lane & 15, lk = (lane >> 4) * 8;

    for (int k0 = 0; k0 < K; k0 += 32) {
        const float* pAr = Ar + (size_t)(arow0 + sar) * lda + k0 + sac;
        const float* pAi = Ai + (size_t)(arow0 + sar) * lda + k0 + sac;
        float4 va_r[4], va_i[4];
        #pragma unroll
        for (int q = 0; q < 4; ++q) { va_r[q] = ld4(pAr + 4*q); va_i[q] = ld4(pAi + 4*q); }
        const float* pBr = Br + (size_t)(brow0 + sbr) * ldb + k0 + sbc;
        const float* pBi = Bi + (size_t)(brow0 + sbr) * ldb + k0 + sbc;
        float4 vb_r[2], vb_i[2];
        #pragma unroll
        for (int q = 0; q < 2; ++q) { vb_r[q] = ld4(pBr + 4*q); vb_i[q] = ld4(pBi + 4*q); }

        __syncthreads();  // prior-iteration readers done before overwrite
        #pragma unroll
        for (int q = 0; q < 4; ++q) {
            *(uint2*)&As_r[sar][sac + 4*q] =
                make_uint2(packbf(va_r[q].x, va_r[q].y), packbf(va_r[q].z, va_r[q].w));
            *(uint2*)&As_i[sar][sac + 4*q] =
                make_uint2(packbf(va_i[q].x, va_i[q].y), packbf(va_i[q].z, va_i[q].w));
        }
        #pragma unroll
        for (int q = 0; q < 2; ++q) {
            *(uint2*)&Bs_r[sbr][sbc + 4*q] =
                make_uint2(packbf(vb_r[q].x, vb_r[q].y), packbf(vb_r[q].z, vb_r[q].w));
            *(uint2*)&Bs_i[sbr][sbc + 4*q] =
                make_uint2(packbf(vb_i[q].x, vb_i[q].y), packbf(vb_i[q].z, vb_i[q].w));
        }
        __syncthreads();

        short8v a_r[4], a_i[4], a_x[4];
        #pragma unroll
        for (int fm = 0; fm < 4; ++fm) {
            a_r[fm] = *(const short8v*)&As_r[wr*64 + fm*16 + lrow][lk];
            a_i[fm] = *(const short8v*)&As_i[wr*64 + fm*16 + lrow][lk];
            a_x[fm] = neg8(CONJB ? a_r[fm] : a_i[fm]);
        }
        short8v b_r[2], b_i[2];
        #pragma unroll
        for (int fn = 0; fn < 2; ++fn) {
            b_r[fn] = *(const short8v*)&Bs_r[wn*32 + fn*16 + lrow][lk];
            b_i[fn] = *(const short8v*)&Bs_i[wn*32 + fn*16 + lrow][lk];
        }
        #pragma unroll
        for (int fm = 0; fm < 4; ++fm)
            #pragma unroll
            for (int fn = 0; fn < 2; ++fn) {
                accr[fm][fn] = __builtin_amdgcn_mfma_f32_16x16x32_bf16(
                    a_r[fm], b_r[fn], accr[fm][fn], 0, 0, 0);
                accr[fm][fn] = __builtin_amdgcn_mfma_f32_16x16x32_bf16(
                    CONJB ? a_i[fm] : a_x[fm], b_i[fn], accr[fm][fn], 0, 0, 0);
                acci[fm][fn] = __builtin_amdgcn_mfma_f32_16x16x32_bf16(
                    CONJB ? a_x[fm] : a_r[fm], b_i[fn], acci[fm][fn], 0, 0, 0);
                acci[fm][fn] = __builtin_amdgcn_mfma_f32_16x16x32_bf16(
                    a_i[fm], b_r[fn], acci[fm][fn], 0, 0, 0);
            }
    }
}

// ======= legacy fp32 VALU GEMM (still used by score_k) =======
template<bool CONJB, int LIMA, int LIMB, class TA, class TB>
__device__ __forceinline__ void cgemm64(
    const TA* __restrict__ Ar, const TA* __restrict__ Ai, int arow0, int lda,
    const TB* __restrict__ Br, const TB* __restrict__ Bi, int brow0, int ldb,
    int K, float accr[4][4], float acci[4][4])
{
    __shared__ float Asr[16][65], Asi[16][65], Bsr[16][65], Bsi[16][65];
    const int tid = threadIdx.x;
    const int tx = tid & 15, ty = tid >> 4;
    const int lr = tid >> 2, lk = (tid & 3) * 4;

    for (int k0 = 0; k0 < K; k0 += 16) {
        const size_t aidx = cmin((size_t)(arow0 + lr) * lda + k0 + lk, (size_t)(LIMA - 4));
        const size_t bidx = cmin((size_t)(brow0 + lr) * ldb + k0 + lk, (size_t)(LIMB - 4));
        float4 a4r = ld4(Ar + aidx);
        float4 a4i = ld4(Ai + aidx);
        float4 b4r = ld4(Br + bidx);
        float4 b4i = ld4(Bi + bidx);
        __syncthreads();
        Asr[lk+0][lr] = a4r.x; Asr[lk+1][lr] = a4r.y; Asr[lk+2][lr] = a4r.z; Asr[lk+3][lr] = a4r.w;
        Asi[lk+0][lr] = a4i.x; Asi[lk+1][lr] = a4i.y; Asi[lk+2][lr] = a4i.z; Asi[lk+3][lr] = a4i.w;
        Bsr[lk+0][lr] = b4r.x; Bsr[lk+1][lr] = b4r.y; Bsr[lk+2][lr] = b4r.z; Bsr[lk+3][lr] = b4r.w;
        Bsi[lk+0][lr] = b4i.x; Bsi[lk+1][lr] = b4i.y; Bsi[lk+2][lr] = b4i.z; Bsi[lk+3][lr] = b4i.w;
        __syncthreads();
        #pragma unroll
        for (int kk = 0; kk < 16; ++kk) {
            float ar[4], ai[4], br_[4], bi_[4];
            #pragma unroll
            for (int i = 0; i < 4; ++i) { ar[i] = Asr[kk][ty + 16*i]; ai[i] = Asi[kk][ty + 16*i]; }
            #pragma unroll
            for (int j = 0; j < 4; ++j) { br_[j] = Bsr[kk][tx + 16*j]; bi_[j] = Bsi[kk][tx + 16*j]; }
            #pragma unroll
            for (int i = 0; i < 4; ++i)
                #pragma unroll
                for (int j = 0; j < 4; ++j) {
                    if (CONJB) {
                        accr[i][j] = fmaf(ar[i], br_[j], fmaf( ai[i], bi_[j], accr[i][j]));
                        acci[i][j] = fmaf(ai[i], br_[j], fmaf(-ar[i], bi_[j], acci[i][j]));
                    } else {
                        accr[i][j] = fmaf(ar[i], br_[j], fmaf(-ai[i], bi_[j], accr[i][j]));
                        acci[i][j] = fmaf(ar[i], bi_[j], fmaf( ai[i], br_[j], acci[i][j]));
                    }
                }
        }
    }
}

// ---- diagnostic ----
__global__ void diag_k(float* __restrict__ out, float v) { out[0] = v; }

// ---- K1: QKV projection (MFMA) -> bf16 planes. grid (M/128, E/64, 3) ----
__global__ __launch_bounds__(256) void qkv_proj_k(
    const float* __restrict__ xr, const float* __restrict__ xi,
    const float* __restrict__ wqr, const float* __restrict__ wqi,
    const float* __restrict__ bqr, const float* __restrict__ bqi,
    const float* __restrict__ wkr, const float* __restrict__ wki,
    const float* __restrict__ bkr, const float* __restrict__ bki,
    const float* __restrict__ wvr, const float* __restrict__ wvi,
    const float* __restrict__ bvr, const float* __restrict__ bvi,
    unsigned short* __restrict__ ws)
{
    const int which = blockIdx.z;
    const float* wr_ = which == 0 ? wqr : which == 1 ? wkr : wvr;
    const float* wi_ = which == 0 ? wqi : which == 1 ? wki : wvi;
    const float* br_ = which == 0 ? bqr : which == 1 ? bkr : bvr;
    const float* bi_ = which == 0 ? bqi : which == 1 ? bki : bvi;
    unsigned short* outr = ws + (size_t)which * 2 * Qsz;
    unsigned short* outi = outr + Qsz;

    const int m0 = blockIdx.x * 128, n0 = blockIdx.y * 64;
    f32x4 accr[4][2], acci[4][2];
    const f32x4 z4 = {0.f, 0.f, 0.f, 0.f};
    #pragma unroll
    for (int fm = 0; fm < 4; ++fm)
        #pragma unroll
        for (int fn = 0; fn < 2; ++fn) { accr[fm][fn] = z4; acci[fm][fn] = z4; }

    cgemm_mfma<false>(xr, xi, m0, Fn, wr_, wi_, n0, Fn, Fn, accr, acci);

    const int lane = threadIdx.x & 63, wid = threadIdx.x >> 6;
    const int wr2 = wid >> 1, wn2 = wid & 1;
    #pragma unroll
    for (int fm = 0; fm < 4; ++fm)
        #pragma unroll
        for (int fn = 0; fn < 2; ++fn) {
            const int e = n0 + wn2*32 + fn*16 + (lane & 15);
            const int h = e >> 6, c = e & (Cn - 1);
            const float brv = br_[e], biv = bi_[e];
            #pragma unroll
            for (int r = 0; r < 4; ++r) {
                const int m = m0 + wr2*64 + fm*16 + (lane >> 4)*4 + r;
                const int b = m >> 10, s = m & (Sn - 1);
                const size_t idx = (((size_t)(b * Hn + h)) * Sn + s) * Cn + c;
                outr[idx] = f2bf(accr[fm][fn][r] + brv);
                outi[idx] = f2bf(acci[fm][fn][r] + biv);
            }
        }
}

// ---- K2: |q.conj(k)|/sqrt(2C) -> attn slot (stride ST). grid (S/64,S/64,64) ----
template<int ST>
__global__ __launch_bounds__(256) void score_k(
    const unsigned short* __restrict__ qkv, float* __restrict__ attn)
{
    const int bh = blockIdx.z;
    const int r0 = blockIdx.x * 64, t0 = blockIdx.y * 64;
    const int row0 = bh * Sn;

    float accr[4][4] = {}, acci[4][4] = {};
    cgemm64<true, Qszi, Qszi>(qkv, qkv + Qsz, row0 + r0, Cn,
                              qkv + 2 * Qsz, qkv + 3 * Qsz, row0 + t0, Cn,
                              Cn, accr, acci);

    const size_t ATTF = ATT1 * ST;
    const int tx = threadIdx.x & 15, ty = threadIdx.x >> 4;
    #pragma unroll
    for (int i = 0; i < 4; ++i) {
        const size_t row = (size_t)bh * Sn + r0 + ty + 16*i;
        #pragma unroll
        for (int j = 0; j < 4; ++j) {
            const int t = t0 + tx + 16*j;
            const float mag = sqrtf(fmaf(accr[i][j], accr[i][j], acci[i][j]*acci[i][j])) * RDIV;
            const size_t idx = cmin((row * Sn + t) * (size_t)ST, ATTF - ST);
            if (ST == 2) *(float2*)&attn[idx] = make_float2(mag, 0.f);
            else         attn[idx] = mag;
        }
    }
}

// ---- K3: in-place row softmax (stride ST). grid (S/4, 64), 1 wave/row ----
template<int ST>
__global__ __launch_bounds__(256) void softmax_k(float* __restrict__ attn)
{
    const int bh = blockIdx.y;
    const int wid = threadIdx.x >> 6, lane = threadIdx.x & 63;
    const int row = blockIdx.x * 4 + wid;
    const size_t rbase = ((size_t)bh * Sn + row) * Sn;
    const size_t ATTF = ATT1 * ST;

    float v[16];
    float mx = -1e30f;
    #pragma unroll
    for (int j = 0; j < 16; ++j) {
        v[j] = attn[cmin((rbase + lane + 64*j) * (size_t)ST, ATTF - ST)];
        mx = fmaxf(mx, v[j]);
    }
    #pragma unroll
    for (int m = 32; m >= 1; m >>= 1) mx = fmaxf(mx, __shfl_xor(mx, m));
    float sum = 0.f;
    #pragma unroll
    for (int j = 0; j < 16; ++j) { v[j] = __expf(v[j] - mx); sum += v[j]; }
    #pragma unroll
    for (int m = 32; m >= 1; m >>= 1) sum += __shfl_xor(sum, m);
    const float inv = 1.f / sum;
    #pragma unroll
    for (int j = 0; j < 16; ++j)
        attn[cmin((rbase + lane + 64*j) * (size_t)ST, ATTF - ST)] = v[j] * inv;
}

// ---- K4: av = attn @ conj(v) (attn stride ST) -> fp32 planes. grid (S/32, 64) ----
template<int ST>
__global__ __launch_bounds__(256) void av_k(
    const unsigned short* __restrict__ qkv, const float* __restrict__ attn,
    float* __restrict__ av)
{
    const int bh = blockIdx.y;
    const int r0 = blockIdx.x * 32;
    const size_t off = (size_t)bh * Sn * Cn;
    const unsigned short* vr = qkv + 4 * Qsz;
    const unsigned short* vi = qkv + 5 * Qsz;
    const size_t abase = ((size_t)bh * Sn + r0) * Sn;
    const size_t ATTF = ATT1 * ST;

    __shared__ float ps[32][64];
    __shared__ float vsr[64][64], vsi[64][64];

    const int tid = threadIdx.x;
    const int rg = tid >> 5;
    const int cp = tid & 31;
    const int pr = tid >> 3;
    const int pt = (tid & 7) * 8;
    const int st = tid >> 4;
    const int sc0 = (tid & 15) * 4;

    float ar_[4][2] = {}, ai_[4][2] = {};

    for (int tt = 0; tt < Sn; tt += 64) {
        __syncthreads();
        #pragma unroll
        for (int j = 0; j < 8; ++j)
            ps[pr][pt + j] = attn[cmin((abase + (size_t)pr * Sn + tt + pt + j) * (size_t)ST, ATTF - ST)];
        #pragma unroll
        for (int rep = 0; rep < 4; ++rep) {
            const int t = st + rep * 16;
            const size_t vidx = cmin(off + (size_t)(tt + t) * Cn + sc0, Qsz - 4);
            *(float4*)&vsr[t][sc0] = ld4(vr + vidx);
            *(float4*)&vsi[t][sc0] = ld4(vi + vidx);
        }
        __syncthreads();
        #pragma unroll 4
        for (int t = 0; t < 64; ++t) {
            const float2 v_r = *(const float2*)&vsr[t][2*cp];
            const float2 v_i = *(const float2*)&vsi[t][2*cp];
            #pragma unroll
            for (int i = 0; i < 4; ++i) {
                const float p = ps[rg*4 + i][t];
                ar_[i][0] = fmaf(p, v_r.x, ar_[i][0]);
                ar_[i][1] = fmaf(p, v_r.y, ar_[i][1]);
                ai_[i][0] = fmaf(p, v_i.x, ai_[i][0]);
                ai_[i][1] = fmaf(p, v_i.y, ai_[i][1]);
            }
        }
    }
    const int b = bh >> 3, h = bh & 7;
    #pragma unroll
    for (int i = 0; i < 4; ++i) {
        const int srow = r0 + rg*4 + i;
        const size_t base = cmin(((size_t)(b * Sn + srow)) * En + h * Cn + 2*cp, Qsz - 2);
        *(float2*)&av[base]       = make_float2( ar_[i][0],  ar_[i][1]);
        *(float2*)&av[Qsz + base] = make_float2(-ai_[i][0], -ai_[i][1]);  // conj(v)
    }
}

// ---- K5: out = av x wo^T + bo (MFMA, out stride ST). grid (M/128, F/64) ----
template<int ST>
__global__ __launch_bounds__(256) void out_proj_k(
    const float* __restrict__ avr, const float* __restrict__ avi,
    const float* __restrict__ wor, const float* __restrict__ woi,
    const float* __restrict__ bor, const float* __restrict__ boi,
    float* __restrict__ out)
{
    const int m0 = blockIdx.x * 128, n0 = blockIdx.y * 64;
    f32x4 accr[4][2], acci[4][2];
    const f32x4 z4 = {0.f, 0.f, 0.f, 0.f};
    #pragma unroll
    for (int fm = 0; fm < 4; ++fm)
        #pragma unroll
        for (int fn = 0; fn < 2; ++fn) { accr[fm][fn] = z4; acci[fm][fn] = z4; }

    cgemm_mfma<false>(avr, avi, m0, En, wor, woi, n0, En, En, accr, acci);

    const int lane = threadIdx.x & 63, wid = threadIdx.x >> 6;
    const int wr2 = wid >> 1, wn2 = wid & 1;
    #pragma unroll
    for (int fm = 0; fm < 4; ++fm)
        #pragma unroll
        for (int fn = 0; fn < 2; ++fn) {
            const int f = n0 + wn2*32 + fn*16 + (lane & 15);
            const float brv = bor[f], biv = boi[f];
            #pragma unroll
            for (int r = 0; r < 4; ++r) {
                const int m = m0 + wr2*64 + fm*16 + (lane >> 4)*4 + r;
                const size_t idx = ((size_t)m * Fn + f) * (size_t)ST;
                if (ST == 2)
                    *(float2*)&out[idx] = make_float2(accr[fm][fn][r] + brv, acci[fm][fn][r] + biv);
                else
                    out[idx] = accr[fm][fn][r] + brv;
            }
        }
}

template<int ST>
static void launch_all(const float* xr, const float* xi,
                       const float* wqr, const float* wqi, const float* bqr, const float* bqi,
                       const float* wkr, const float* wki, const float* bkr, const float* bki,
                       const float* wvr, const float* wvi, const float* bvr, const float* bvi,
                       const float* wor, const float* woi, const float* bor, const float* boi,
                       unsigned short* qkv, float* av, float* out, hipStream_t stream)
{
    float* attn = out + OUT1 * ST;
    qkv_proj_k<<<dim3(Mn/128, En/64, 3), 256, 0, stream>>>(
        xr, xi, wqr, wqi, bqr, bqi, wkr, wki, bkr, bki, wvr, wvi, bvr, bvi, qkv);
    score_k<ST><<<dim3(Sn/64, Sn/64, Bn*Hn), 256, 0, stream>>>(qkv, attn);
    softmax_k<ST><<<dim3(Sn/4, Bn*Hn), 256, 0, stream>>>(attn);
    av_k<ST><<<dim3(Sn/32, Bn*Hn), 256, 0, stream>>>(qkv, attn, av);
    out_proj_k<ST><<<dim3(Mn/128, Fn/64), 256, 0, stream>>>(
        av, av + Qsz, wor, woi, bor, boi, out);
}

extern "C" void kernel_launch(void* const* d_in, const int* in_sizes, int n_in,
                              void* d_out, int out_size, void* d_ws, size_t ws_size,
                              hipStream_t stream)
{
    // ---- host-side guards (validated r4/r6; keep) ----
    bool sizes_ok = (n_in == 18);
    if (sizes_ok) {
        sizes_ok = in_sizes[0] == XLIM && in_sizes[1] == XLIM;
        for (int g = 0; g < 3 && sizes_ok; ++g) {
            sizes_ok = in_sizes[2 + 4*g] == WLIM && in_sizes[3 + 4*g] == WLIM &&
                       in_sizes[4 + 4*g] == En  && in_sizes[5 + 4*g] == En;
        }
        sizes_ok = sizes_ok && in_sizes[14] == WLIM && in_sizes[15] == WLIM &&
                   in_sizes[16] == Fn && in_sizes[17] == Fn;
    }
    const size_t ws_needed = 6 * Qsz * sizeof(unsigned short);  // 48 MiB
    const bool ws_ok = (d_ws != nullptr) && (ws_size >= ws_needed);

    const long long fullF = 2LL * (long long)(OUT1 + ATT1);  // 142,606,336 floats
    const long long realF = (long long)(OUT1 + ATT1);        //  71,303,168 floats
    const int st = ((long long)out_size == fullF) ? 2
                 : ((long long)out_size == realF) ? 1 : 0;

    if (!sizes_ok || !ws_ok || st == 0) {
        float diag = !sizes_ok ? 3.0e9f
                   : !ws_ok    ? (float)(double)ws_size
                               : (float)out_size;
        diag_k<<<1, 1, 0, stream>>>((float*)d_out, diag);
        return;
    }

    const float* xr  = (const float*)d_in[0];
    const float* xi  = (const float*)d_in[1];
    const float* wqr = (const float*)d_in[2];
    const float* wqi = (const float*)d_in[3];
    const float* bqr = (const float*)d_in[4];
    const float* bqi = (const float*)d_in[5];
    const float* wkr = (const float*)d_in[6];
    const float* wki = (const float*)d_in[7];
    const float* bkr = (const float*)d_in[8];
    const float* bki = (const float*)d_in[9];
    const float* wvr = (const float*)d_in[10];
    const float* wvi = (const float*)d_in[11];
    const float* bvr = (const float*)d_in[12];
    const float* bvi = (const float*)d_in[13];
    const float* wor = (const float*)d_in[14];
    const float* woi = (const float*)d_in[15];
    const float* bor = (const float*)d_in[16];
    const float* boi = (const float*)d_in[17];

    // ws: 6 bf16 planes of Qsz (q_r,q_i,k_r,k_i,v_r,v_i) = 48 MiB.
    // After score_k, q+k planes are dead; av fp32 (2*Qsz floats = 32 MiB) overlays them.
    unsigned short* qkv = (unsigned short*)d_ws;
    float* av = (float*)d_ws;
    float* out = (float*)d_out;

    if (st == 2)
        launch_all<2>(xr, xi, wqr, wqi, bqr, bqi, wkr, wki, bkr, bki,
                      wvr, wvi, bvr, bvi, wor, woi, bor, boi, qkv, av, out, stream);
    else
        launch_all<1>(xr, xi, wqr, wqi, bqr, bqi, wkr, wki, bkr, bki,
                      wvr, wvi, bvr, bvi, wor, woi, bor, boi, qkv, av, out, stream);
}

// Round 8
// 588.985 us; speedup vs baseline: 2.6593x; 1.5517x over previous
//
#include <hip/hip_runtime.h>

// ComplexMultiheadAttention: B=8,S=1024,F=512,E=512,H=8,C=64
// Round 8: MFMA score_k. r7 PASSED (914 us): qkv/out_proj MFMA verified
// (absmax 0.0195). Top kernel now score_k (431 us, MfmaUtil=0, VALUBusy=84%,
// 8.4M bank conflicts) = last fp32-VALU GEMM. Convert it to the same
// 128x64/4-wave/BK=32 MFMA structure; q/k planes are already bf16 in ws so
// staging is direct short8 copies. Legacy cgemm64 removed.
//  K1 qkv_proj (MFMA fp32->bf16), K2 score (MFMA bf16), K3 softmax,
//  K4 av (fp32 VALU), K5 out_proj (MFMA).

namespace {
constexpr int Bn = 8, Sn = 1024, Fn = 512, En = 512, Hn = 8, Cn = 64;
constexpr int Mn = Bn * Sn;                       // 8192
constexpr int Qszi = Bn * Hn * Sn * Cn;           // 4,194,304 per plane
constexpr size_t Qsz = (size_t)Qszi;
constexpr int XLIM = Bn * Sn * Fn;                // floats per x plane
constexpr int WLIM = En * Fn;                     // floats per weight plane
constexpr size_t OUT1 = (size_t)Bn * Sn * Fn;     // complex elems in out   (4,194,304)
constexpr size_t ATT1 = (size_t)Bn * Hn * Sn * Sn;// complex elems in attn (67,108,864)
constexpr float RDIV = 0.08838834764831845f;      // 1/sqrt(2*C) = 1/sqrt(128)
}

typedef __attribute__((ext_vector_type(8))) short short8v;  // 8 bf16 (4 VGPRs)
typedef __attribute__((ext_vector_type(4))) float f32x4;

__device__ __forceinline__ size_t cmin(size_t i, size_t lim) { return i < lim ? i : lim; }

__device__ __forceinline__ float bf2f(unsigned short u) {
    union { unsigned int u32; float f; } c; c.u32 = (unsigned int)u << 16; return c.f;
}
__device__ __forceinline__ unsigned short f2bf(float f) {
    union { float f; unsigned int u; } c; c.f = f;
    unsigned int r = (c.u + 0x7FFFu + ((c.u >> 16) & 1u)) >> 16;  // RNE
    return (unsigned short)r;
}
__device__ __forceinline__ unsigned int packbf(float lo, float hi) {
    return (unsigned int)f2bf(lo) | ((unsigned int)f2bf(hi) << 16);
}
__device__ __forceinline__ short8v neg8(short8v v) {
    union { short8v s; unsigned int u[4]; } c; c.s = v;
    #pragma unroll
    for (int j = 0; j < 4; ++j) c.u[j] ^= 0x80008000u;
    return c.s;
}

__device__ __forceinline__ float4 ld4(const float* p) { return *(const float4*)p; }
__device__ __forceinline__ float4 ld4(const unsigned short* p) {
    ushort4 v = *(const ushort4*)p;  // 8 B load
    return make_float4(bf2f(v.x), bf2f(v.y), bf2f(v.z), bf2f(v.w));
}

// ================= shared MFMA inner body =================
// Per wave: 64x32 output = 4x2 fragments of 16x16x32. LDS tiles padded to 40
// shorts/row (2-way bank alias = free). Complex product via 4 real MFMAs.
template<bool CONJB>
__device__ __forceinline__ void mfma_body(
    const short (*As_r)[40], const short (*As_i)[40],
    const short (*Bs_r)[40], const short (*Bs_i)[40],
    int wr, int wn, int lrow, int lk,
    f32x4 accr[4][2], f32x4 acci[4][2])
{
    short8v a_r[4], a_i[4], a_x[4];
    #pragma unroll
    for (int fm = 0; fm < 4; ++fm) {
        a_r[fm] = *(const short8v*)&As_r[wr*64 + fm*16 + lrow][lk];
        a_i[fm] = *(const short8v*)&As_i[wr*64 + fm*16 + lrow][lk];
        a_x[fm] = neg8(CONJB ? a_r[fm] : a_i[fm]);
    }
    short8v b_r[2], b_i[2];
    #pragma unroll
    for (int fn = 0; fn < 2; ++fn) {
        b_r[fn] = *(const short8v*)&Bs_r[wn*32 + fn*16 + lrow][lk];
        b_i[fn] = *(const short8v*)&Bs_i[wn*32 + fn*16 + lrow][lk];
    }
    #pragma unroll
    for (int fm = 0; fm < 4; ++fm)
        #pragma unroll
        for (int fn = 0; fn < 2; ++fn) {
            accr[fm][fn] = __builtin_amdgcn_mfma_f32_16x16x32_bf16(
                a_r[fm], b_r[fn], accr[fm][fn], 0, 0, 0);
            accr[fm][fn] = __builtin_amdgcn_mfma_f32_16x16x32_bf16(
                CONJB ? a_i[fm] : a_x[fm], b_i[fn], accr[fm][fn], 0, 0, 0);
            acci[fm][fn] = __builtin_amdgcn_mfma_f32_16x16x32_bf16(
                CONJB ? a_x[fm] : a_r[fm], b_i[fn], acci[fm][fn], 0, 0, 0);
            acci[fm][fn] = __builtin_amdgcn_mfma_f32_16x16x32_bf16(
                a_i[fm], b_r[fn], acci[fm][fn], 0, 0, 0);
        }
}

// ===== MFMA complex NT GEMM, fp32 inputs (convert to bf16 at staging) =====
// 128x64 tile, 256 threads = 4 waves (2x2), BK=32.
template<bool CONJB>
__device__ __forceinline__ void cgemm_mfma(
    const float* __restrict__ Ar, const float* __restrict__ Ai, int arow0, int lda,
    const float* __restrict__ Br, const float* __restrict__ Bi, int brow0, int ldb,
    int K, f32x4 accr[4][2], f32x4 acci[4][2])
{
    __shared__ short As_r[128][40], As_i[128][40];
    __shared__ short Bs_r[64][40],  Bs_i[64][40];   // total 30 KB LDS
    const int tid = threadIdx.x;
    const int sar = tid >> 1, sac = (tid & 1) * 16;  // A stage: 2 thr/row, 16 cols
    const int sbr = tid >> 2, sbc = (tid & 3) * 8;   // B stage: 4 thr/row, 8 cols
    const int wid = tid >> 6, lane = tid & 63;
    const int wr = wid >> 1, wn = wid & 1;
    const int lrow = lane & 15, lk = (lane >> 4) * 8;

    for (int k0 = 0; k0 < K; k0 += 32) {
        const float* pAr = Ar + (size_t)(arow0 + sar) * lda + k0 + sac;
        const float* pAi = Ai + (size_t)(arow0 + sar) * lda + k0 + sac;
        float4 va_r[4], va_i[4];
        #pragma unroll
        for (int q = 0; q < 4; ++q) { va_r[q] = ld4(pAr + 4*q); va_i[q] = ld4(pAi + 4*q); }
        const float* pBr = Br + (size_t)(brow0 + sbr) * ldb + k0 + sbc;
        const float* pBi = Bi + (size_t)(brow0 + sbr) * ldb + k0 + sbc;
        float4 vb_r[2], vb_i[2];
        #pragma unroll
        for (int q = 0; q < 2; ++q) { vb_r[q] = ld4(pBr + 4*q); vb_i[q] = ld4(pBi + 4*q); }

        __syncthreads();  // prior-iteration readers done before overwrite
        #pragma unroll
        for (int q = 0; q < 4; ++q) {
            *(uint2*)&As_r[sar][sac + 4*q] =
                make_uint2(packbf(va_r[q].x, va_r[q].y), packbf(va_r[q].z, va_r[q].w));
            *(uint2*)&As_i[sar][sac + 4*q] =
                make_uint2(packbf(va_i[q].x, va_i[q].y), packbf(va_i[q].z, va_i[q].w));
        }
        #pragma unroll
        for (int q = 0; q < 2; ++q) {
            *(uint2*)&Bs_r[sbr][sbc + 4*q] =
                make_uint2(packbf(vb_r[q].x, vb_r[q].y), packbf(vb_r[q].z, vb_r[q].w));
            *(uint2*)&Bs_i[sbr][sbc + 4*q] =
                make_uint2(packbf(vb_i[q].x, vb_i[q].y), packbf(vb_i[q].z, vb_i[q].w));
        }
        __syncthreads();
        mfma_body<CONJB>(As_r, As_i, Bs_r, Bs_i, wr, wn, lrow, lk, accr, acci);
    }
}

// ===== MFMA complex NT GEMM, bf16 inputs (direct short8 staging) =====
template<bool CONJB>
__device__ __forceinline__ void cgemm_mfma_bf16(
    const unsigned short* __restrict__ Ar, const unsigned short* __restrict__ Ai,
    int arow0, int lda,
    const unsigned short* __restrict__ Br, const unsigned short* __restrict__ Bi,
    int brow0, int ldb,
    int K, f32x4 accr[4][2], f32x4 acci[4][2])
{
    __shared__ short As_r[128][40], As_i[128][40];
    __shared__ short Bs_r[64][40],  Bs_i[64][40];
    const int tid = threadIdx.x;
    const int sar = tid >> 1, sac = (tid & 1) * 16;  // 2 thr/row, 16 shorts each
    const int sbr = tid >> 2, sbc = (tid & 3) * 8;   // 4 thr/row, 8 shorts each
    const int wid = tid >> 6, lane = tid & 63;
    const int wr = wid >> 1, wn = wid & 1;
    const int lrow = lane & 15, lk = (lane >> 4) * 8;

    for (int k0 = 0; k0 < K; k0 += 32) {
        const unsigned short* pAr = Ar + (size_t)(arow0 + sar) * lda + k0 + sac;
        const unsigned short* pAi = Ai + (size_t)(arow0 + sar) * lda + k0 + sac;
        short8v va_r0 = *(const short8v*)pAr;
        short8v va_r1 = *(const short8v*)(pAr + 8);
        short8v va_i0 = *(const short8v*)pAi;
        short8v va_i1 = *(const short8v*)(pAi + 8);
        const unsigned short* pBr = Br + (size_t)(brow0 + sbr) * ldb + k0 + sbc;
        const unsigned short* pBi = Bi + (size_t)(brow0 + sbr) * ldb + k0 + sbc;
        short8v vb_r = *(const short8v*)pBr;
        short8v vb_i = *(const short8v*)pBi;

        __syncthreads();
        *(short8v*)&As_r[sar][sac]     = va_r0;
        *(short8v*)&As_r[sar][sac + 8] = va_r1;
        *(short8v*)&As_i[sar][sac]     = va_i0;
        *(short8v*)&As_i[sar][sac + 8] = va_i1;
        *(short8v*)&Bs_r[sbr][sbc] = vb_r;
        *(short8v*)&Bs_i[sbr][sbc] = vb_i;
        __syncthreads();
        mfma_body<CONJB>(As_r, As_i, Bs_r, Bs_i, wr, wn, lrow, lk, accr, acci);
    }
}

// ---- diagnostic ----
__global__ void diag_k(float* __restrict__ out, float v) { out[0] = v; }

// ---- K1: QKV projection (MFMA) -> bf16 planes. grid (M/128, E/64, 3) ----
__global__ __launch_bounds__(256) void qkv_proj_k(
    const float* __restrict__ xr, const float* __restrict__ xi,
    const float* __restrict__ wqr, const float* __restrict__ wqi,
    const float* __restrict__ bqr, const float* __restrict__ bqi,
    const float* __restrict__ wkr, const float* __restrict__ wki,
    const float* __restrict__ bkr, const float* __restrict__ bki,
    const float* __restrict__ wvr, const float* __restrict__ wvi,
    const float* __restrict__ bvr, const float* __restrict__ bvi,
    unsigned short* __restrict__ ws)
{
    const int which = blockIdx.z;
    const float* wr_ = which == 0 ? wqr : which == 1 ? wkr : wvr;
    const float* wi_ = which == 0 ? wqi : which == 1 ? wki : wvi;
    const float* br_ = which == 0 ? bqr : which == 1 ? bkr : bvr;
    const float* bi_ = which == 0 ? bqi : which == 1 ? bkr : bvi;
    // NOTE: fixed potential typo hazard explicitly:
    bi_ = which == 0 ? bqi : which == 1 ? bki : bvi;
    unsigned short* outr = ws + (size_t)which * 2 * Qsz;
    unsigned short* outi = outr + Qsz;

    const int m0 = blockIdx.x * 128, n0 = blockIdx.y * 64;
    f32x4 accr[4][2], acci[4][2];
    const f32x4 z4 = {0.f, 0.f, 0.f, 0.f};
    #pragma unroll
    for (int fm = 0; fm < 4; ++fm)
        #pragma unroll
        for (int fn = 0; fn < 2; ++fn) { accr[fm][fn] = z4; acci[fm][fn] = z4; }

    cgemm_mfma<false>(xr, xi, m0, Fn, wr_, wi_, n0, Fn, Fn, accr, acci);

    const int lane = threadIdx.x & 63, wid = threadIdx.x >> 6;
    const int wr2 = wid >> 1, wn2 = wid & 1;
    #pragma unroll
    for (int fm = 0; fm < 4; ++fm)
        #pragma unroll
        for (int fn = 0; fn < 2; ++fn) {
            const int e = n0 + wn2*32 + fn*16 + (lane & 15);
            const int h = e >> 6, c = e & (Cn - 1);
            const float brv = br_[e], biv = bi_[e];
            #pragma unroll
            for (int r = 0; r < 4; ++r) {
                const int m = m0 + wr2*64 + fm*16 + (lane >> 4)*4 + r;
                const int b = m >> 10, s = m & (Sn - 1);
                const size_t idx = (((size_t)(b * Hn + h)) * Sn + s) * Cn + c;
                outr[idx] = f2bf(accr[fm][fn][r] + brv);
                outi[idx] = f2bf(acci[fm][fn][r] + biv);
            }
        }
}

// ---- K2: score (MFMA): |q.conj(k)|/sqrt(2C) -> attn. grid (S/128, S/64, 64) ----
template<int ST>
__global__ __launch_bounds__(256) void score_k(
    const unsigned short* __restrict__ qkv, float* __restrict__ attn)
{
    const int bh = blockIdx.z;
    const int r0 = blockIdx.x * 128, t0 = blockIdx.y * 64;
    const int row0 = bh * Sn;

    f32x4 accr[4][2], acci[4][2];
    const f32x4 z4 = {0.f, 0.f, 0.f, 0.f};
    #pragma unroll
    for (int fm = 0; fm < 4; ++fm)
        #pragma unroll
        for (int fn = 0; fn < 2; ++fn) { accr[fm][fn] = z4; acci[fm][fn] = z4; }

    cgemm_mfma_bf16<true>(qkv, qkv + Qsz, row0 + r0, Cn,
                          qkv + 2 * Qsz, qkv + 3 * Qsz, row0 + t0, Cn,
                          Cn, accr, acci);

    const size_t ATTF = ATT1 * ST;
    const int lane = threadIdx.x & 63, wid = threadIdx.x >> 6;
    const int wr2 = wid >> 1, wn2 = wid & 1;
    #pragma unroll
    for (int fm = 0; fm < 4; ++fm)
        #pragma unroll
        for (int fn = 0; fn < 2; ++fn) {
            const int t = t0 + wn2*32 + fn*16 + (lane & 15);
            #pragma unroll
            for (int r = 0; r < 4; ++r) {
                const int srow = r0 + wr2*64 + fm*16 + (lane >> 4)*4 + r;
                const size_t row = (size_t)bh * Sn + srow;
                const float re = accr[fm][fn][r], im = acci[fm][fn][r];
                const float mag = sqrtf(fmaf(re, re, im*im)) * RDIV;
                const size_t idx = cmin((row * Sn + t) * (size_t)ST, ATTF - ST);
                if (ST == 2) *(float2*)&attn[idx] = make_float2(mag, 0.f);
                else         attn[idx] = mag;
            }
        }
}

// ---- K3: in-place row softmax (stride ST). grid (S/4, 64), 1 wave/row ----
template<int ST>
__global__ __launch_bounds__(256) void softmax_k(float* __restrict__ attn)
{
    const int bh = blockIdx.y;
    const int wid = threadIdx.x >> 6, lane = threadIdx.x & 63;
    const int row = blockIdx.x * 4 + wid;
    const size_t rbase = ((size_t)bh * Sn + row) * Sn;
    const size_t ATTF = ATT1 * ST;

    float v[16];
    float mx = -1e30f;
    #pragma unroll
    for (int j = 0; j < 16; ++j) {
        v[j] = attn[cmin((rbase + lane + 64*j) * (size_t)ST, ATTF - ST)];
        mx = fmaxf(mx, v[j]);
    }
    #pragma unroll
    for (int m = 32; m >= 1; m >>= 1) mx = fmaxf(mx, __shfl_xor(mx, m));
    float sum = 0.f;
    #pragma unroll
    for (int j = 0; j < 16; ++j) { v[j] = __expf(v[j] - mx); sum += v[j]; }
    #pragma unroll
    for (int m = 32; m >= 1; m >>= 1) sum += __shfl_xor(sum, m);
    const float inv = 1.f / sum;
    #pragma unroll
    for (int j = 0; j < 16; ++j)
        attn[cmin((rbase + lane + 64*j) * (size_t)ST, ATTF - ST)] = v[j] * inv;
}

// ---- K4: av = attn @ conj(v) (attn stride ST) -> fp32 planes. grid (S/32, 64) ----
template<int ST>
__global__ __launch_bounds__(256) void av_k(
    const unsigned short* __restrict__ qkv, const float* __restrict__ attn,
    float* __restrict__ av)
{
    const int bh = blockIdx.y;
    const int r0 = blockIdx.x * 32;
    const size_t off = (size_t)bh * Sn * Cn;
    const unsigned short* vr = qkv + 4 * Qsz;
    const unsigned short* vi = qkv + 5 * Qsz;
    const size_t abase = ((size_t)bh * Sn + r0) * Sn;
    const size_t ATTF = ATT1 * ST;

    __shared__ float ps[32][64];
    __shared__ float vsr[64][64], vsi[64][64];

    const int tid = threadIdx.x;
    const int rg = tid >> 5;
    const int cp = tid & 31;
    const int pr = tid >> 3;
    const int pt = (tid & 7) * 8;
    const int st = tid >> 4;
    const int sc0 = (tid & 15) * 4;

    float ar_[4][2] = {}, ai_[4][2] = {};

    for (int tt = 0; tt < Sn; tt += 64) {
        __syncthreads();
        #pragma unroll
        for (int j = 0; j < 8; ++j)
            ps[pr][pt + j] = attn[cmin((abase + (size_t)pr * Sn + tt + pt + j) * (size_t)ST, ATTF - ST)];
        #pragma unroll
        for (int rep = 0; rep < 4; ++rep) {
            const int t = st + rep * 16;
            const size_t vidx = cmin(off + (size_t)(tt + t) * Cn + sc0, Qsz - 4);
            *(float4*)&vsr[t][sc0] = ld4(vr + vidx);
            *(float4*)&vsi[t][sc0] = ld4(vi + vidx);
        }
        __syncthreads();
        #pragma unroll 4
        for (int t = 0; t < 64; ++t) {
            const float2 v_r = *(const float2*)&vsr[t][2*cp];
            const float2 v_i = *(const float2*)&vsi[t][2*cp];
            #pragma unroll
            for (int i = 0; i < 4; ++i) {
                const float p = ps[rg*4 + i][t];
                ar_[i][0] = fmaf(p, v_r.x, ar_[i][0]);
                ar_[i][1] = fmaf(p, v_r.y, ar_[i][1]);
                ai_[i][0] = fmaf(p, v_i.x, ai_[i][0]);
                ai_[i][1] = fmaf(p, v_i.y, ai_[i][1]);
            }
        }
    }
    const int b = bh >> 3, h = bh & 7;
    #pragma unroll
    for (int i = 0; i < 4; ++i) {
        const int srow = r0 + rg*4 + i;
        const size_t base = cmin(((size_t)(b * Sn + srow)) * En + h * Cn + 2*cp, Qsz - 2);
        *(float2*)&av[base]       = make_float2( ar_[i][0],  ar_[i][1]);
        *(float2*)&av[Qsz + base] = make_float2(-ai_[i][0], -ai_[i][1]);  // conj(v)
    }
}

// ---- K5: out = av x wo^T + bo (MFMA, out stride ST). grid (M/128, F/64) ----
template<int ST>
__global__ __launch_bounds__(256) void out_proj_k(
    const float* __restrict__ avr, const float* __restrict__ avi,
    const float* __restrict__ wor, const float* __restrict__ woi,
    const float* __restrict__ bor, const float* __restrict__ boi,
    float* __restrict__ out)
{
    const int m0 = blockIdx.x * 128, n0 = blockIdx.y * 64;
    f32x4 accr[4][2], acci[4][2];
    const f32x4 z4 = {0.f, 0.f, 0.f, 0.f};
    #pragma unroll
    for (int fm = 0; fm < 4; ++fm)
        #pragma unroll
        for (int fn = 0; fn < 2; ++fn) { accr[fm][fn] = z4; acci[fm][fn] = z4; }

    cgemm_mfma<false>(avr, avi, m0, En, wor, woi, n0, En, En, accr, acci);

    const int lane = threadIdx.x & 63, wid = threadIdx.x >> 6;
    const int wr2 = wid >> 1, wn2 = wid & 1;
    #pragma unroll
    for (int fm = 0; fm < 4; ++fm)
        #pragma unroll
        for (int fn = 0; fn < 2; ++fn) {
            const int f = n0 + wn2*32 + fn*16 + (lane & 15);
            const float brv = bor[f], biv = boi[f];
            #pragma unroll
            for (int r = 0; r < 4; ++r) {
                const int m = m0 + wr2*64 + fm*16 + (lane >> 4)*4 + r;
                const size_t idx = ((size_t)m * Fn + f) * (size_t)ST;
                if (ST == 2)
                    *(float2*)&out[idx] = make_float2(accr[fm][fn][r] + brv, acci[fm][fn][r] + biv);
                else
                    out[idx] = accr[fm][fn][r] + brv;
            }
        }
}

template<int ST>
static void launch_all(const float* xr, const float* xi,
                       const float* wqr, const float* wqi, const float* bqr, const float* bqi,
                       const float* wkr, const float* wki, const float* bkr, const float* bki,
                       const float* wvr, const float* wvi, const float* bvr, const float* bvi,
                       const float* wor, const float* woi, const float* bor, const float* boi,
                       unsigned short* qkv, float* av, float* out, hipStream_t stream)
{
    float* attn = out + OUT1 * ST;
    qkv_proj_k<<<dim3(Mn/128, En/64, 3), 256, 0, stream>>>(
        xr, xi, wqr, wqi, bqr, bqi, wkr, wki, bkr, bki, wvr, wvi, bvr, bvi, qkv);
    score_k<ST><<<dim3(Sn/128, Sn/64, Bn*Hn), 256, 0, stream>>>(qkv, attn);
    softmax_k<ST><<<dim3(Sn/4, Bn*Hn), 256, 0, stream>>>(attn);
    av_k<ST><<<dim3(Sn/32, Bn*Hn), 256, 0, stream>>>(qkv, attn, av);
    out_proj_k<ST><<<dim3(Mn/128, Fn/64), 256, 0, stream>>>(
        av, av + Qsz, wor, woi, bor, boi, out);
}

extern "C" void kernel_launch(void* const* d_in, const int* in_sizes, int n_in,
                              void* d_out, int out_size, void* d_ws, size_t ws_size,
                              hipStream_t stream)
{
    // ---- host-side guards (validated r4/r6; keep) ----
    bool sizes_ok = (n_in == 18);
    if (sizes_ok) {
        sizes_ok = in_sizes[0] == XLIM && in_sizes[1] == XLIM;
        for (int g = 0; g < 3 && sizes_ok; ++g) {
            sizes_ok = in_sizes[2 + 4*g] == WLIM && in_sizes[3 + 4*g] == WLIM &&
                       in_sizes[4 + 4*g] == En  && in_sizes[5 + 4*g] == En;
        }
        sizes_ok = sizes_ok && in_sizes[14] == WLIM && in_sizes[15] == WLIM &&
                   in_sizes[16] == Fn && in_sizes[17] == Fn;
    }
    const size_t ws_needed = 6 * Qsz * sizeof(unsigned short);  // 48 MiB
    const bool ws_ok = (d_ws != nullptr) && (ws_size >= ws_needed);

    const long long fullF = 2LL * (long long)(OUT1 + ATT1);  // 142,606,336 floats
    const long long realF = (long long)(OUT1 + ATT1);        //  71,303,168 floats
    const int st = ((long long)out_size == fullF) ? 2
                 : ((long long)out_size == realF) ? 1 : 0;

    if (!sizes_ok || !ws_ok || st == 0) {
        float diag = !sizes_ok ? 3.0e9f
                   : !ws_ok    ? (float)(double)ws_size
                               : (float)out_size;
        diag_k<<<1, 1, 0, stream>>>((float*)d_out, diag);
        return;
    }

    const float* xr  = (const float*)d_in[0];
    const float* xi  = (const float*)d_in[1];
    const float* wqr = (const float*)d_in[2];
    const float* wqi = (const float*)d_in[3];
    const float* bqr = (const float*)d_in[4];
    const float* bqi = (const float*)d_in[5];
    const float* wkr = (const float*)d_in[6];
    const float* wki = (const float*)d_in[7];
    const float* bkr = (const float*)d_in[8];
    const float* bki = (const float*)d_in[9];
    const float* wvr = (const float*)d_in[10];
    const float* wvi = (const float*)d_in[11];
    const float* bvr = (const float*)d_in[12];
    const float* bvi = (const float*)d_in[13];
    const float* wor = (const float*)d_in[14];
    const float* woi = (const float*)d_in[15];
    const float* bor = (const float*)d_in[16];
    const float* boi = (const float*)d_in[17];

    // ws: 6 bf16 planes of Qsz (q_r,q_i,k_r,k_i,v_r,v_i) = 48 MiB.
    // After score_k, q+k planes are dead; av fp32 (2*Qsz floats = 32 MiB) overlays them.
    unsigned short* qkv = (unsigned short*)d_ws;
    float* av = (float*)d_ws;
    float* out = (float*)d_out;

    if (st == 2)
        launch_all<2>(xr, xi, wqr, wqi, bqr, bqi, wkr, wki, bkr, bki,
                      wvr, wvi, bvr, bvi, wor, woi, bor, boi, qkv, av, out, stream);
    else
        launch_all<1>(xr, xi, wqr, wqi, bqr, bqi, wkr, wki, bkr, bki,
                      wvr, wvi, bvr, bvi, wor, woi, bor, boi, qkv, av, out, stream);
}

// Round 10
// 394.512 us; speedup vs baseline: 3.9702x; 1.4929x over previous
//
#include <hip/hip_runtime.h>

// ComplexMultiheadAttention: B=8,S=1024,F=512,E=512,H=8,C=64
// Round 10: RESUBMIT of round 9 (UnresponsiveContainer infra failure — no
// signal; kernel unchanged for blame isolation on the av_k MFMA conversion).
// r8 PASSED (589 us). Top kernel av_k (310 us, MfmaUtil=0, VALUBusy=55%) =
// last fp32-VALU GEMM (P x conj(V), 17 GF). Convert to MFMA: A = P rows
// (bf16, converted from attn fp32 at staging), B = V^T tile (bf16
// scatter-transpose at staging), 2 real MFMAs per frag, epilogue negates
// imag (conj). av becomes attn-read-bound (~536 MB).
//  K1 qkv_proj (MFMA), K2 score (MFMA), K3 softmax, K4 av (MFMA), K5 out (MFMA).

namespace {
constexpr int Bn = 8, Sn = 1024, Fn = 512, En = 512, Hn = 8, Cn = 64;
constexpr int Mn = Bn * Sn;                       // 8192
constexpr int Qszi = Bn * Hn * Sn * Cn;           // 4,194,304 per plane
constexpr size_t Qsz = (size_t)Qszi;
constexpr int XLIM = Bn * Sn * Fn;                // floats per x plane
constexpr int WLIM = En * Fn;                     // floats per weight plane
constexpr size_t OUT1 = (size_t)Bn * Sn * Fn;     // complex elems in out   (4,194,304)
constexpr size_t ATT1 = (size_t)Bn * Hn * Sn * Sn;// complex elems in attn (67,108,864)
constexpr float RDIV = 0.08838834764831845f;      // 1/sqrt(2*C) = 1/sqrt(128)
}

typedef __attribute__((ext_vector_type(8))) short short8v;  // 8 bf16 (4 VGPRs)
typedef __attribute__((ext_vector_type(4))) float f32x4;

__device__ __forceinline__ size_t cmin(size_t i, size_t lim) { return i < lim ? i : lim; }

__device__ __forceinline__ float bf2f(unsigned short u) {
    union { unsigned int u32; float f; } c; c.u32 = (unsigned int)u << 16; return c.f;
}
__device__ __forceinline__ unsigned short f2bf(float f) {
    union { float f; unsigned int u; } c; c.f = f;
    unsigned int r = (c.u + 0x7FFFu + ((c.u >> 16) & 1u)) >> 16;  // RNE
    return (unsigned short)r;
}
__device__ __forceinline__ unsigned int packbf(float lo, float hi) {
    return (unsigned int)f2bf(lo) | ((unsigned int)f2bf(hi) << 16);
}
__device__ __forceinline__ short8v neg8(short8v v) {
    union { short8v s; unsigned int u[4]; } c; c.s = v;
    #pragma unroll
    for (int j = 0; j < 4; ++j) c.u[j] ^= 0x80008000u;
    return c.s;
}

__device__ __forceinline__ float4 ld4(const float* p) { return *(const float4*)p; }
__device__ __forceinline__ float4 ld4(const unsigned short* p) {
    ushort4 v = *(const ushort4*)p;  // 8 B load
    return make_float4(bf2f(v.x), bf2f(v.y), bf2f(v.z), bf2f(v.w));
}

// ================= shared MFMA inner body (complex x complex) =================
template<bool CONJB>
__device__ __forceinline__ void mfma_body(
    const short (*As_r)[40], const short (*As_i)[40],
    const short (*Bs_r)[40], const short (*Bs_i)[40],
    int wr, int wn, int lrow, int lk,
    f32x4 accr[4][2], f32x4 acci[4][2])
{
    short8v a_r[4], a_i[4], a_x[4];
    #pragma unroll
    for (int fm = 0; fm < 4; ++fm) {
        a_r[fm] = *(const short8v*)&As_r[wr*64 + fm*16 + lrow][lk];
        a_i[fm] = *(const short8v*)&As_i[wr*64 + fm*16 + lrow][lk];
        a_x[fm] = neg8(CONJB ? a_r[fm] : a_i[fm]);
    }
    short8v b_r[2], b_i[2];
    #pragma unroll
    for (int fn = 0; fn < 2; ++fn) {
        b_r[fn] = *(const short8v*)&Bs_r[wn*32 + fn*16 + lrow][lk];
        b_i[fn] = *(const short8v*)&Bs_i[wn*32 + fn*16 + lrow][lk];
    }
    #pragma unroll
    for (int fm = 0; fm < 4; ++fm)
        #pragma unroll
        for (int fn = 0; fn < 2; ++fn) {
            accr[fm][fn] = __builtin_amdgcn_mfma_f32_16x16x32_bf16(
                a_r[fm], b_r[fn], accr[fm][fn], 0, 0, 0);
            accr[fm][fn] = __builtin_amdgcn_mfma_f32_16x16x32_bf16(
                CONJB ? a_i[fm] : a_x[fm], b_i[fn], accr[fm][fn], 0, 0, 0);
            acci[fm][fn] = __builtin_amdgcn_mfma_f32_16x16x32_bf16(
                CONJB ? a_x[fm] : a_r[fm], b_i[fn], acci[fm][fn], 0, 0, 0);
            acci[fm][fn] = __builtin_amdgcn_mfma_f32_16x16x32_bf16(
                a_i[fm], b_r[fn], acci[fm][fn], 0, 0, 0);
        }
}

// ===== MFMA complex NT GEMM, fp32 inputs (convert to bf16 at staging) =====
template<bool CONJB>
__device__ __forceinline__ void cgemm_mfma(
    const float* __restrict__ Ar, const float* __restrict__ Ai, int arow0, int lda,
    const float* __restrict__ Br, const float* __restrict__ Bi, int brow0, int ldb,
    int K, f32x4 accr[4][2], f32x4 acci[4][2])
{
    __shared__ short As_r[128][40], As_i[128][40];
    __shared__ short Bs_r[64][40],  Bs_i[64][40];   // total 30 KB LDS
    const int tid = threadIdx.x;
    const int sar = tid >> 1, sac = (tid & 1) * 16;
    const int sbr = tid >> 2, sbc = (tid & 3) * 8;
    const int wid = tid >> 6, lane = tid & 63;
    const int wr = wid >> 1, wn = wid & 1;
    const int lrow = lane & 15, lk = (lane >> 4) * 8;

    for (int k0 = 0; k0 < K; k0 += 32) {
        const float* pAr = Ar + (size_t)(arow0 + sar) * lda + k0 + sac;
        const float* pAi = Ai + (size_t)(arow0 + sar) * lda + k0 + sac;
        float4 va_r[4], va_i[4];
        #pragma unroll
        for (int q = 0; q < 4; ++q) { va_r[q] = ld4(pAr + 4*q); va_i[q] = ld4(pAi + 4*q); }
        const float* pBr = Br + (size_t)(brow0 + sbr) * ldb + k0 + sbc;
        const float* pBi = Bi + (size_t)(brow0 + sbr) * ldb + k0 + sbc;
        float4 vb_r[2], vb_i[2];
        #pragma unroll
        for (int q = 0; q < 2; ++q) { vb_r[q] = ld4(pBr + 4*q); vb_i[q] = ld4(pBi + 4*q); }

        __syncthreads();
        #pragma unroll
        for (int q = 0; q < 4; ++q) {
            *(uint2*)&As_r[sar][sac + 4*q] =
                make_uint2(packbf(va_r[q].x, va_r[q].y), packbf(va_r[q].z, va_r[q].w));
            *(uint2*)&As_i[sar][sac + 4*q] =
                make_uint2(packbf(va_i[q].x, va_i[q].y), packbf(va_i[q].z, va_i[q].w));
        }
        #pragma unroll
        for (int q = 0; q < 2; ++q) {
            *(uint2*)&Bs_r[sbr][sbc + 4*q] =
                make_uint2(packbf(vb_r[q].x, vb_r[q].y), packbf(vb_r[q].z, vb_r[q].w));
            *(uint2*)&Bs_i[sbr][sbc + 4*q] =
                make_uint2(packbf(vb_i[q].x, vb_i[q].y), packbf(vb_i[q].z, vb_i[q].w));
        }
        __syncthreads();
        mfma_body<CONJB>(As_r, As_i, Bs_r, Bs_i, wr, wn, lrow, lk, accr, acci);
    }
}

// ===== MFMA complex NT GEMM, bf16 inputs (direct short8 staging) =====
template<bool CONJB>
__device__ __forceinline__ void cgemm_mfma_bf16(
    const unsigned short* __restrict__ Ar, const unsigned short* __restrict__ Ai,
    int arow0, int lda,
    const unsigned short* __restrict__ Br, const unsigned short* __restrict__ Bi,
    int brow0, int ldb,
    int K, f32x4 accr[4][2], f32x4 acci[4][2])
{
    __shared__ short As_r[128][40], As_i[128][40];
    __shared__ short Bs_r[64][40],  Bs_i[64][40];
    const int tid = threadIdx.x;
    const int sar = tid >> 1, sac = (tid & 1) * 16;
    const int sbr = tid >> 2, sbc = (tid & 3) * 8;
    const int wid = tid >> 6, lane = tid & 63;
    const int wr = wid >> 1, wn = wid & 1;
    const int lrow = lane & 15, lk = (lane >> 4) * 8;

    for (int k0 = 0; k0 < K; k0 += 32) {
        const unsigned short* pAr = Ar + (size_t)(arow0 + sar) * lda + k0 + sac;
        const unsigned short* pAi = Ai + (size_t)(arow0 + sar) * lda + k0 + sac;
        short8v va_r0 = *(const short8v*)pAr;
        short8v va_r1 = *(const short8v*)(pAr + 8);
        short8v va_i0 = *(const short8v*)pAi;
        short8v va_i1 = *(const short8v*)(pAi + 8);
        const unsigned short* pBr = Br + (size_t)(brow0 + sbr) * ldb + k0 + sbc;
        const unsigned short* pBi = Bi + (size_t)(brow0 + sbr) * ldb + k0 + sbc;
        short8v vb_r = *(const short8v*)pBr;
        short8v vb_i = *(const short8v*)pBi;

        __syncthreads();
        *(short8v*)&As_r[sar][sac]     = va_r0;
        *(short8v*)&As_r[sar][sac + 8] = va_r1;
        *(short8v*)&As_i[sar][sac]     = va_i0;
        *(short8v*)&As_i[sar][sac + 8] = va_i1;
        *(short8v*)&Bs_r[sbr][sbc] = vb_r;
        *(short8v*)&Bs_i[sbr][sbc] = vb_i;
        __syncthreads();
        mfma_body<CONJB>(As_r, As_i, Bs_r, Bs_i, wr, wn, lrow, lk, accr, acci);
    }
}

// ---- diagnostic ----
__global__ void diag_k(float* __restrict__ out, float v) { out[0] = v; }

// ---- K1: QKV projection (MFMA) -> bf16 planes. grid (M/128, E/64, 3) ----
__global__ __launch_bounds__(256) void qkv_proj_k(
    const float* __restrict__ xr, const float* __restrict__ xi,
    const float* __restrict__ wqr, const float* __restrict__ wqi,
    const float* __restrict__ bqr, const float* __restrict__ bqi,
    const float* __restrict__ wkr, const float* __restrict__ wki,
    const float* __restrict__ bkr, const float* __restrict__ bki,
    const float* __restrict__ wvr, const float* __restrict__ wvi,
    const float* __restrict__ bvr, const float* __restrict__ bvi,
    unsigned short* __restrict__ ws)
{
    const int which = blockIdx.z;
    const float* wr_ = which == 0 ? wqr : which == 1 ? wkr : wvr;
    const float* wi_ = which == 0 ? wqi : which == 1 ? wki : wvi;
    const float* br_ = which == 0 ? bqr : which == 1 ? bkr : bvr;
    const float* bi_ = which == 0 ? bqi : which == 1 ? bki : bvi;
    unsigned short* outr = ws + (size_t)which * 2 * Qsz;
    unsigned short* outi = outr + Qsz;

    const int m0 = blockIdx.x * 128, n0 = blockIdx.y * 64;
    f32x4 accr[4][2], acci[4][2];
    const f32x4 z4 = {0.f, 0.f, 0.f, 0.f};
    #pragma unroll
    for (int fm = 0; fm < 4; ++fm)
        #pragma unroll
        for (int fn = 0; fn < 2; ++fn) { accr[fm][fn] = z4; acci[fm][fn] = z4; }

    cgemm_mfma<false>(xr, xi, m0, Fn, wr_, wi_, n0, Fn, Fn, accr, acci);

    const int lane = threadIdx.x & 63, wid = threadIdx.x >> 6;
    const int wr2 = wid >> 1, wn2 = wid & 1;
    #pragma unroll
    for (int fm = 0; fm < 4; ++fm)
        #pragma unroll
        for (int fn = 0; fn < 2; ++fn) {
            const int e = n0 + wn2*32 + fn*16 + (lane & 15);
            const int h = e >> 6, c = e & (Cn - 1);
            const float brv = br_[e], biv = bi_[e];
            #pragma unroll
            for (int r = 0; r < 4; ++r) {
                const int m = m0 + wr2*64 + fm*16 + (lane >> 4)*4 + r;
                const int b = m >> 10, s = m & (Sn - 1);
                const size_t idx = (((size_t)(b * Hn + h)) * Sn + s) * Cn + c;
                outr[idx] = f2bf(accr[fm][fn][r] + brv);
                outi[idx] = f2bf(acci[fm][fn][r] + biv);
            }
        }
}

// ---- K2: score (MFMA): |q.conj(k)|/sqrt(2C) -> attn. grid (S/128, S/64, 64) ----
template<int ST>
__global__ __launch_bounds__(256) void score_k(
    const unsigned short* __restrict__ qkv, float* __restrict__ attn)
{
    const int bh = blockIdx.z;
    const int r0 = blockIdx.x * 128, t0 = blockIdx.y * 64;
    const int row0 = bh * Sn;

    f32x4 accr[4][2], acci[4][2];
    const f32x4 z4 = {0.f, 0.f, 0.f, 0.f};
    #pragma unroll
    for (int fm = 0; fm < 4; ++fm)
        #pragma unroll
        for (int fn = 0; fn < 2; ++fn) { accr[fm][fn] = z4; acci[fm][fn] = z4; }

    cgemm_mfma_bf16<true>(qkv, qkv + Qsz, row0 + r0, Cn,
                          qkv + 2 * Qsz, qkv + 3 * Qsz, row0 + t0, Cn,
                          Cn, accr, acci);

    const size_t ATTF = ATT1 * ST;
    const int lane = threadIdx.x & 63, wid = threadIdx.x >> 6;
    const int wr2 = wid >> 1, wn2 = wid & 1;
    #pragma unroll
    for (int fm = 0; fm < 4; ++fm)
        #pragma unroll
        for (int fn = 0; fn < 2; ++fn) {
            const int t = t0 + wn2*32 + fn*16 + (lane & 15);
            #pragma unroll
            for (int r = 0; r < 4; ++r) {
                const int srow = r0 + wr2*64 + fm*16 + (lane >> 4)*4 + r;
                const size_t row = (size_t)bh * Sn + srow;
                const float re = accr[fm][fn][r], im = acci[fm][fn][r];
                const float mag = sqrtf(fmaf(re, re, im*im)) * RDIV;
                const size_t idx = cmin((row * Sn + t) * (size_t)ST, ATTF - ST);
                if (ST == 2) *(float2*)&attn[idx] = make_float2(mag, 0.f);
                else         attn[idx] = mag;
            }
        }
}

// ---- K3: in-place row softmax (stride ST). grid (S/4, 64), 1 wave/row ----
template<int ST>
__global__ __launch_bounds__(256) void softmax_k(float* __restrict__ attn)
{
    const int bh = blockIdx.y;
    const int wid = threadIdx.x >> 6, lane = threadIdx.x & 63;
    const int row = blockIdx.x * 4 + wid;
    const size_t rbase = ((size_t)bh * Sn + row) * Sn;
    const size_t ATTF = ATT1 * ST;

    float v[16];
    float mx = -1e30f;
    #pragma unroll
    for (int j = 0; j < 16; ++j) {
        v[j] = attn[cmin((rbase + lane + 64*j) * (size_t)ST, ATTF - ST)];
        mx = fmaxf(mx, v[j]);
    }
    #pragma unroll
    for (int m = 32; m >= 1; m >>= 1) mx = fmaxf(mx, __shfl_xor(mx, m));
    float sum = 0.f;
    #pragma unroll
    for (int j = 0; j < 16; ++j) { v[j] = __expf(v[j] - mx); sum += v[j]; }
    #pragma unroll
    for (int m = 32; m >= 1; m >>= 1) sum += __shfl_xor(sum, m);
    const float inv = 1.f / sum;
    #pragma unroll
    for (int j = 0; j < 16; ++j)
        attn[cmin((rbase + lane + 64*j) * (size_t)ST, ATTF - ST)] = v[j] * inv;
}

// ---- K4: av = P x conj(V) via MFMA. grid (S/128, 64), block 256 (4 waves 2x2) ----
// A = P rows (bf16 from attn fp32), B = V^T tile (scatter-transposed bf16).
// acc[m=r][n=c]; av_r = acc_r, av_i = -acc_i (conj V, P real).
template<int ST>
__global__ __launch_bounds__(256) void av_k(
    const unsigned short* __restrict__ qkv, const float* __restrict__ attn,
    float* __restrict__ av)
{
    const int bh = blockIdx.y;
    const int r0 = blockIdx.x * 128;
    const size_t voff = (size_t)bh * Sn * Cn;
    const unsigned short* vr = qkv + 4 * Qsz + voff;
    const unsigned short* vi = qkv + 5 * Qsz + voff;
    const size_t abase = ((size_t)bh * Sn + r0) * Sn;  // complex-elem index

    __shared__ short Ps[128][40];                 // P tile (BK=32 + pad)
    __shared__ short Vtr[64][40], Vti[64][40];    // V^T tiles: [c][t]

    const int tid = threadIdx.x;
    const int spr = tid >> 1, spt = (tid & 1) * 16;   // P: 2 thr/row, 16 t each
    const int svt = tid & 31, svc = (tid >> 5) * 8;   // V: t lane, c octet
    const int wid = tid >> 6, lane = tid & 63;
    const int wr = wid >> 1, wn = wid & 1;
    const int lrow = lane & 15, lk = (lane >> 4) * 8;

    f32x4 accr[4][2], acci[4][2];
    const f32x4 z4 = {0.f, 0.f, 0.f, 0.f};
    #pragma unroll
    for (int fm = 0; fm < 4; ++fm)
        #pragma unroll
        for (int fn = 0; fn < 2; ++fn) { accr[fm][fn] = z4; acci[fm][fn] = z4; }

    for (int t0 = 0; t0 < Sn; t0 += 32) {
        // load 16 P values (row spr, t = t0+spt..+16) from attn
        float pv[16];
        if (ST == 2) {
            const float4* ap4 = (const float4*)((const float2*)attn +
                                 (abase + (size_t)spr * Sn + t0 + spt));
            #pragma unroll
            for (int q = 0; q < 8; ++q) { float4 v4 = ap4[q]; pv[2*q] = v4.x; pv[2*q+1] = v4.z; }
        } else {
            const float* ap = attn + abase + (size_t)spr * Sn + t0 + spt;
            #pragma unroll
            for (int q = 0; q < 4; ++q) {
                float4 v4 = *(const float4*)(ap + 4*q);
                pv[4*q] = v4.x; pv[4*q+1] = v4.y; pv[4*q+2] = v4.z; pv[4*q+3] = v4.w;
            }
        }
        // load V rows for transpose: vr/vi[(t0+svt)*Cn + svc .. +8)
        short8v vvr = *(const short8v*)(vr + (size_t)(t0 + svt) * Cn + svc);
        short8v vvi = *(const short8v*)(vi + (size_t)(t0 + svt) * Cn + svc);

        __syncthreads();
        #pragma unroll
        for (int q = 0; q < 4; ++q)
            *(unsigned int*)&Ps[spr][spt + 4*q] =
                (unsigned int)f2bf(pv[4*q])     | ((unsigned int)f2bf(pv[4*q+1]) << 16),
            *(unsigned int*)&Ps[spr][spt + 4*q + 2] =
                (unsigned int)f2bf(pv[4*q+2])   | ((unsigned int)f2bf(pv[4*q+3]) << 16);
        #pragma unroll
        for (int j = 0; j < 8; ++j) {
            Vtr[svc + j][svt] = vvr[j];
            Vti[svc + j][svt] = vvi[j];
        }
        __syncthreads();

        short8v pA[4];
        #pragma unroll
        for (int fm = 0; fm < 4; ++fm)
            pA[fm] = *(const short8v*)&Ps[wr*64 + fm*16 + lrow][lk];
        short8v bR[2], bI[2];
        #pragma unroll
        for (int fn = 0; fn < 2; ++fn) {
            bR[fn] = *(const short8v*)&Vtr[wn*32 + fn*16 + lrow][lk];
            bI[fn] = *(const short8v*)&Vti[wn*32 + fn*16 + lrow][lk];
        }
        #pragma unroll
        for (int fm = 0; fm < 4; ++fm)
            #pragma unroll
            for (int fn = 0; fn < 2; ++fn) {
                accr[fm][fn] = __builtin_amdgcn_mfma_f32_16x16x32_bf16(
                    pA[fm], bR[fn], accr[fm][fn], 0, 0, 0);
                acci[fm][fn] = __builtin_amdgcn_mfma_f32_16x16x32_bf16(
                    pA[fm], bI[fn], acci[fm][fn], 0, 0, 0);
            }
    }

    const int b = bh >> 3, h = bh & 7;
    #pragma unroll
    for (int fm = 0; fm < 4; ++fm)
        #pragma unroll
        for (int fn = 0; fn < 2; ++fn) {
            const int c = wn*32 + fn*16 + (lane & 15);
            #pragma unroll
            for (int r = 0; r < 4; ++r) {
                const int srow = r0 + wr*64 + fm*16 + (lane >> 4)*4 + r;
                const size_t base = ((size_t)(b * Sn + srow)) * En + h * Cn + c;
                av[base]       =  accr[fm][fn][r];
                av[Qsz + base] = -acci[fm][fn][r];  // conj(v)
            }
        }
}

// ---- K5: out = av x wo^T + bo (MFMA, out stride ST). grid (M/128, F/64) ----
template<int ST>
__global__ __launch_bounds__(256) void out_proj_k(
    const float* __restrict__ avr, const float* __restrict__ avi,
    const float* __restrict__ wor, const float* __restrict__ woi,
    const float* __restrict__ bor, const float* __restrict__ boi,
    float* __restrict__ out)
{
    const int m0 = blockIdx.x * 128, n0 = blockIdx.y * 64;
    f32x4 accr[4][2], acci[4][2];
    const f32x4 z4 = {0.f, 0.f, 0.f, 0.f};
    #pragma unroll
    for (int fm = 0; fm < 4; ++fm)
        #pragma unroll
        for (int fn = 0; fn < 2; ++fn) { accr[fm][fn] = z4; acci[fm][fn] = z4; }

    cgemm_mfma<false>(avr, avi, m0, En, wor, woi, n0, En, En, accr, acci);

    const int lane = threadIdx.x & 63, wid = threadIdx.x >> 6;
    const int wr2 = wid >> 1, wn2 = wid & 1;
    #pragma unroll
    for (int fm = 0; fm < 4; ++fm)
        #pragma unroll
        for (int fn = 0; fn < 2; ++fn) {
            const int f = n0 + wn2*32 + fn*16 + (lane & 15);
            const float brv = bor[f], biv = boi[f];
            #pragma unroll
            for (int r = 0; r < 4; ++r) {
                const int m = m0 + wr2*64 + fm*16 + (lane >> 4)*4 + r;
                const size_t idx = ((size_t)m * Fn + f) * (size_t)ST;
                if (ST == 2)
                    *(float2*)&out[idx] = make_float2(accr[fm][fn][r] + brv, acci[fm][fn][r] + biv);
                else
                    out[idx] = accr[fm][fn][r] + brv;
            }
        }
}

template<int ST>
static void launch_all(const float* xr, const float* xi,
                       const float* wqr, const float* wqi, const float* bqr, const float* bqi,
                       const float* wkr, const float* wki, const float* bkr, const float* bki,
                       const float* wvr, const float* wvi, const float* bvr, const float* bvi,
                       const float* wor, const float* woi, const float* bor, const float* boi,
                       unsigned short* qkv, float* av, float* out, hipStream_t stream)
{
    float* attn = out + OUT1 * ST;
    qkv_proj_k<<<dim3(Mn/128, En/64, 3), 256, 0, stream>>>(
        xr, xi, wqr, wqi, bqr, bqi, wkr, wki, bkr, bki, wvr, wvi, bvr, bvi, qkv);
    score_k<ST><<<dim3(Sn/128, Sn/64, Bn*Hn), 256, 0, stream>>>(qkv, attn);
    softmax_k<ST><<<dim3(Sn/4, Bn*Hn), 256, 0, stream>>>(attn);
    av_k<ST><<<dim3(Sn/128, Bn*Hn), 256, 0, stream>>>(qkv, attn, av);
    out_proj_k<ST><<<dim3(Mn/128, Fn/64), 256, 0, stream>>>(
        av, av + Qsz, wor, woi, bor, boi, out);
}

extern "C" void kernel_launch(void* const* d_in, const int* in_sizes, int n_in,
                              void* d_out, int out_size, void* d_ws, size_t ws_size,
                              hipStream_t stream)
{
    // ---- host-side guards (validated r4/r6; keep) ----
    bool sizes_ok = (n_in == 18);
    if (sizes_ok) {
        sizes_ok = in_sizes[0] == XLIM && in_sizes[1] == XLIM;
        for (int g = 0; g < 3 && sizes_ok; ++g) {
            sizes_ok = in_sizes[2 + 4*g] == WLIM && in_sizes[3 + 4*g] == WLIM &&
                       in_sizes[4 + 4*g] == En  && in_sizes[5 + 4*g] == En;
        }
        sizes_ok = sizes_ok && in_sizes[14] == WLIM && in_sizes[15] == WLIM &&
                   in_sizes[16] == Fn && in_sizes[17] == Fn;
    }
    const size_t ws_needed = 6 * Qsz * sizeof(unsigned short);  // 48 MiB
    const bool ws_ok = (d_ws != nullptr) && (ws_size >= ws_needed);

    const long long fullF = 2LL * (long long)(OUT1 + ATT1);  // 142,606,336 floats
    const long long realF = (long long)(OUT1 + ATT1);        //  71,303,168 floats
    const int st = ((long long)out_size == fullF) ? 2
                 : ((long long)out_size == realF) ? 1 : 0;

    if (!sizes_ok || !ws_ok || st == 0) {
        float diag = !sizes_ok ? 3.0e9f
                   : !ws_ok    ? (float)(double)ws_size
                               : (float)out_size;
        diag_k<<<1, 1, 0, stream>>>((float*)d_out, diag);
        return;
    }

    const float* xr  = (const float*)d_in[0];
    const float* xi  = (const float*)d_in[1];
    const float* wqr = (const float*)d_in[2];
    const float* wqi = (const float*)d_in[3];
    const float* bqr = (const float*)d_in[4];
    const float* bqi = (const float*)d_in[5];
    const float* wkr = (const float*)d_in[6];
    const float* wki = (const float*)d_in[7];
    const float* bkr = (const float*)d_in[8];
    const float* bki = (const float*)d_in[9];
    const float* wvr = (const float*)d_in[10];
    const float* wvi = (const float*)d_in[11];
    const float* bvr = (const float*)d_in[12];
    const float* bvi = (const float*)d_in[13];
    const float* wor = (const float*)d_in[14];
    const float* woi = (const float*)d_in[15];
    const float* bor = (const float*)d_in[16];
    const float* boi = (const float*)d_in[17];

    // ws: 6 bf16 planes of Qsz (q_r,q_i,k_r,k_i,v_r,v_i) = 48 MiB.
    // After score_k, q+k planes are dead; av fp32 (2*Qsz floats = 32 MiB) overlays them.
    unsigned short* qkv = (unsigned short*)d_ws;
    float* av = (float*)d_ws;
    float* out = (float*)d_out;

    if (st == 2)
        launch_all<2>(xr, xi, wqr, wqi, bqr, bqi, wkr, wki, bkr, bki,
                      wvr, wvi, bvr, bvi, wor, woi, bor, boi, qkv, av, out, stream);
    else
        launch_all<1>(xr, xi, wqr, wqi, bqr, bqi, wkr, wki, bkr, bki,
                      wvr, wvi, bvr, bvi, wor, woi, bor, boi, qkv, av, out, stream);
}

// Round 12
// 317.408 us; speedup vs baseline: 4.9347x; 1.2429x over previous
//
#include <hip/hip_runtime.h>

// ComplexMultiheadAttention: B=8,S=1024,F=512,E=512,H=8,C=64
// Round 12: RESUBMIT of round 11 (UnresponsiveContainer infra failure, same
// container as r1/r9 — no signal; kernel unchanged for blame isolation on the
// fusion). r10 PASSED (394 us; implied: qkv ~75, score ~55, softmax ~65,
// av ~115, out ~40). score+softmax+av move >1.6 GB of HBM for P that is cheap
// to recompute (34 GF MFMA ~ 55 us at measured 625 TF effective).
// attn_fused_k: per 128-row strip x head: Pass A = score MFMA, accumulate
// row sums of exp(mag) (NO max pass: mag>=0 bounded ~22, exp safe in fp32;
// softmax shift-invariant). Pass B = recompute scores, P=exp*inv, write
// normalized attn once (mandatory), stage P->LDS bf16 (overlay K after
// barrier), PV MFMA -> av bf16 planes 6,7 (ws demand 64 MiB, guarded).
// out_proj reads bf16 A directly (halved fetch).

namespace {
constexpr int Bn = 8, Sn = 1024, Fn = 512, En = 512, Hn = 8, Cn = 64;
constexpr int Mn = Bn * Sn;                       // 8192
constexpr int Qszi = Bn * Hn * Sn * Cn;           // 4,194,304 per plane
constexpr size_t Qsz = (size_t)Qszi;
constexpr int XLIM = Bn * Sn * Fn;                // floats per x plane
constexpr int WLIM = En * Fn;                     // floats per weight plane
constexpr size_t OUT1 = (size_t)Bn * Sn * Fn;     // complex elems in out   (4,194,304)
constexpr size_t ATT1 = (size_t)Bn * Hn * Sn * Sn;// complex elems in attn (67,108,864)
constexpr float RDIV = 0.08838834764831845f;      // 1/sqrt(2*C) = 1/sqrt(128)
}

typedef __attribute__((ext_vector_type(8))) short short8v;  // 8 bf16 (4 VGPRs)
typedef __attribute__((ext_vector_type(4))) float f32x4;

__device__ __forceinline__ float bf2f(unsigned short u) {
    union { unsigned int u32; float f; } c; c.u32 = (unsigned int)u << 16; return c.f;
}
__device__ __forceinline__ unsigned short f2bf(float f) {
    union { float f; unsigned int u; } c; c.f = f;
    unsigned int r = (c.u + 0x7FFFu + ((c.u >> 16) & 1u)) >> 16;  // RNE
    return (unsigned short)r;
}
__device__ __forceinline__ unsigned int packbf(float lo, float hi) {
    return (unsigned int)f2bf(lo) | ((unsigned int)f2bf(hi) << 16);
}
__device__ __forceinline__ short8v neg8(short8v v) {
    union { short8v s; unsigned int u[4]; } c; c.s = v;
    #pragma unroll
    for (int j = 0; j < 4; ++j) c.u[j] ^= 0x80008000u;
    return c.s;
}
__device__ __forceinline__ float4 ld4(const float* p) { return *(const float4*)p; }

// ================= shared MFMA inner body (complex x complex, pad-40 tiles) ====
template<bool CONJB>
__device__ __forceinline__ void mfma_body(
    const short (*As_r)[40], const short (*As_i)[40],
    const short (*Bs_r)[40], const short (*Bs_i)[40],
    int wr, int wn, int lrow, int lk,
    f32x4 accr[4][2], f32x4 acci[4][2])
{
    short8v a_r[4], a_i[4], a_x[4];
    #pragma unroll
    for (int fm = 0; fm < 4; ++fm) {
        a_r[fm] = *(const short8v*)&As_r[wr*64 + fm*16 + lrow][lk];
        a_i[fm] = *(const short8v*)&As_i[wr*64 + fm*16 + lrow][lk];
        a_x[fm] = neg8(CONJB ? a_r[fm] : a_i[fm]);
    }
    short8v b_r[2], b_i[2];
    #pragma unroll
    for (int fn = 0; fn < 2; ++fn) {
        b_r[fn] = *(const short8v*)&Bs_r[wn*32 + fn*16 + lrow][lk];
        b_i[fn] = *(const short8v*)&Bs_i[wn*32 + fn*16 + lrow][lk];
    }
    #pragma unroll
    for (int fm = 0; fm < 4; ++fm)
        #pragma unroll
        for (int fn = 0; fn < 2; ++fn) {
            accr[fm][fn] = __builtin_amdgcn_mfma_f32_16x16x32_bf16(
                a_r[fm], b_r[fn], accr[fm][fn], 0, 0, 0);
            accr[fm][fn] = __builtin_amdgcn_mfma_f32_16x16x32_bf16(
                CONJB ? a_i[fm] : a_x[fm], b_i[fn], accr[fm][fn], 0, 0, 0);
            acci[fm][fn] = __builtin_amdgcn_mfma_f32_16x16x32_bf16(
                CONJB ? a_x[fm] : a_r[fm], b_i[fn], acci[fm][fn], 0, 0, 0);
            acci[fm][fn] = __builtin_amdgcn_mfma_f32_16x16x32_bf16(
                a_i[fm], b_r[fn], acci[fm][fn], 0, 0, 0);
        }
}

// ===== MFMA complex NT GEMM, fp32 x fp32 (convert at staging) — qkv_proj =====
template<bool CONJB>
__device__ __forceinline__ void cgemm_mfma(
    const float* __restrict__ Ar, const float* __restrict__ Ai, int arow0, int lda,
    const float* __restrict__ Br, const float* __restrict__ Bi, int brow0, int ldb,
    int K, f32x4 accr[4][2], f32x4 acci[4][2])
{
    __shared__ short As_r[128][40], As_i[128][40];
    __shared__ short Bs_r[64][40],  Bs_i[64][40];
    const int tid = threadIdx.x;
    const int sar = tid >> 1, sac = (tid & 1) * 16;
    const int sbr = tid >> 2, sbc = (tid & 3) * 8;
    const int wid = tid >> 6, lane = tid & 63;
    const int wr = wid >> 1, wn = wid & 1;
    const int lrow = lane & 15, lk = (lane >> 4) * 8;

    for (int k0 = 0; k0 < K; k0 += 32) {
        const float* pAr = Ar + (size_t)(arow0 + sar) * lda + k0 + sac;
        const float* pAi = Ai + (size_t)(arow0 + sar) * lda + k0 + sac;
        float4 va_r[4], va_i[4];
        #pragma unroll
        for (int q = 0; q < 4; ++q) { va_r[q] = ld4(pAr + 4*q); va_i[q] = ld4(pAi + 4*q); }
        const float* pBr = Br + (size_t)(brow0 + sbr) * ldb + k0 + sbc;
        const float* pBi = Bi + (size_t)(brow0 + sbr) * ldb + k0 + sbc;
        float4 vb_r[2], vb_i[2];
        #pragma unroll
        for (int q = 0; q < 2; ++q) { vb_r[q] = ld4(pBr + 4*q); vb_i[q] = ld4(pBi + 4*q); }

        __syncthreads();
        #pragma unroll
        for (int q = 0; q < 4; ++q) {
            *(uint2*)&As_r[sar][sac + 4*q] =
                make_uint2(packbf(va_r[q].x, va_r[q].y), packbf(va_r[q].z, va_r[q].w));
            *(uint2*)&As_i[sar][sac + 4*q] =
                make_uint2(packbf(va_i[q].x, va_i[q].y), packbf(va_i[q].z, va_i[q].w));
        }
        #pragma unroll
        for (int q = 0; q < 2; ++q) {
            *(uint2*)&Bs_r[sbr][sbc + 4*q] =
                make_uint2(packbf(vb_r[q].x, vb_r[q].y), packbf(vb_r[q].z, vb_r[q].w));
            *(uint2*)&Bs_i[sbr][sbc + 4*q] =
                make_uint2(packbf(vb_i[q].x, vb_i[q].y), packbf(vb_i[q].z, vb_i[q].w));
        }
        __syncthreads();
        mfma_body<CONJB>(As_r, As_i, Bs_r, Bs_i, wr, wn, lrow, lk, accr, acci);
    }
}

// ===== MFMA complex NT GEMM, A bf16 (direct) x B fp32 (convert) — out_proj =====
template<bool CONJB>
__device__ __forceinline__ void cgemm_mfma_abf16(
    const unsigned short* __restrict__ Ar, const unsigned short* __restrict__ Ai,
    int arow0, int lda,
    const float* __restrict__ Br, const float* __restrict__ Bi, int brow0, int ldb,
    int K, f32x4 accr[4][2], f32x4 acci[4][2])
{
    __shared__ short As_r[128][40], As_i[128][40];
    __shared__ short Bs_r[64][40],  Bs_i[64][40];
    const int tid = threadIdx.x;
    const int sar = tid >> 1, sac = (tid & 1) * 16;
    const int sbr = tid >> 2, sbc = (tid & 3) * 8;
    const int wid = tid >> 6, lane = tid & 63;
    const int wr = wid >> 1, wn = wid & 1;
    const int lrow = lane & 15, lk = (lane >> 4) * 8;

    for (int k0 = 0; k0 < K; k0 += 32) {
        const unsigned short* pAr = Ar + (size_t)(arow0 + sar) * lda + k0 + sac;
        const unsigned short* pAi = Ai + (size_t)(arow0 + sar) * lda + k0 + sac;
        short8v va_r0 = *(const short8v*)pAr;
        short8v va_r1 = *(const short8v*)(pAr + 8);
        short8v va_i0 = *(const short8v*)pAi;
        short8v va_i1 = *(const short8v*)(pAi + 8);
        const float* pBr = Br + (size_t)(brow0 + sbr) * ldb + k0 + sbc;
        const float* pBi = Bi + (size_t)(brow0 + sbr) * ldb + k0 + sbc;
        float4 vb_r[2], vb_i[2];
        #pragma unroll
        for (int q = 0; q < 2; ++q) { vb_r[q] = ld4(pBr + 4*q); vb_i[q] = ld4(pBi + 4*q); }

        __syncthreads();
        *(short8v*)&As_r[sar][sac]     = va_r0;
        *(short8v*)&As_r[sar][sac + 8] = va_r1;
        *(short8v*)&As_i[sar][sac]     = va_i0;
        *(short8v*)&As_i[sar][sac + 8] = va_i1;
        #pragma unroll
        for (int q = 0; q < 2; ++q) {
            *(uint2*)&Bs_r[sbr][sbc + 4*q] =
                make_uint2(packbf(vb_r[q].x, vb_r[q].y), packbf(vb_r[q].z, vb_r[q].w));
            *(uint2*)&Bs_i[sbr][sbc + 4*q] =
                make_uint2(packbf(vb_i[q].x, vb_i[q].y), packbf(vb_i[q].z, vb_i[q].w));
        }
        __syncthreads();
        mfma_body<CONJB>(As_r, As_i, Bs_r, Bs_i, wr, wn, lrow, lk, accr, acci);
    }
}

// ---- diagnostic ----
__global__ void diag_k(float* __restrict__ out, float v) { out[0] = v; }

// ---- K1: QKV projection (MFMA) -> bf16 planes. grid (M/128, E/64, 3) ----
__global__ __launch_bounds__(256) void qkv_proj_k(
    const float* __restrict__ xr, const float* __restrict__ xi,
    const float* __restrict__ wqr, const float* __restrict__ wqi,
    const float* __restrict__ bqr, const float* __restrict__ bqi,
    const float* __restrict__ wkr, const float* __restrict__ wki,
    const float* __restrict__ bkr, const float* __restrict__ bki,
    const float* __restrict__ wvr, const float* __restrict__ wvi,
    const float* __restrict__ bvr, const float* __restrict__ bvi,
    unsigned short* __restrict__ ws)
{
    const int which = blockIdx.z;
    const float* wr_ = which == 0 ? wqr : which == 1 ? wkr : wvr;
    const float* wi_ = which == 0 ? wqi : which == 1 ? wki : wvi;
    const float* br_ = which == 0 ? bqr : which == 1 ? bkr : bvr;
    const float* bi_ = which == 0 ? bqi : which == 1 ? bki : bvi;
    unsigned short* outr = ws + (size_t)which * 2 * Qsz;
    unsigned short* outi = outr + Qsz;

    const int m0 = blockIdx.x * 128, n0 = blockIdx.y * 64;
    f32x4 accr[4][2], acci[4][2];
    const f32x4 z4 = {0.f, 0.f, 0.f, 0.f};
    #pragma unroll
    for (int fm = 0; fm < 4; ++fm)
        #pragma unroll
        for (int fn = 0; fn < 2; ++fn) { accr[fm][fn] = z4; acci[fm][fn] = z4; }

    cgemm_mfma<false>(xr, xi, m0, Fn, wr_, wi_, n0, Fn, Fn, accr, acci);

    const int lane = threadIdx.x & 63, wid = threadIdx.x >> 6;
    const int wr2 = wid >> 1, wn2 = wid & 1;
    #pragma unroll
    for (int fm = 0; fm < 4; ++fm)
        #pragma unroll
        for (int fn = 0; fn < 2; ++fn) {
            const int e = n0 + wn2*32 + fn*16 + (lane & 15);
            const int h = e >> 6, c = e & (Cn - 1);
            const float brv = br_[e], biv = bi_[e];
            #pragma unroll
            for (int r = 0; r < 4; ++r) {
                const int m = m0 + wr2*64 + fm*16 + (lane >> 4)*4 + r;
                const int b = m >> 10, s = m & (Sn - 1);
                const size_t idx = (((size_t)(b * Hn + h)) * Sn + s) * Cn + c;
                outr[idx] = f2bf(accr[fm][fn][r] + brv);
                outi[idx] = f2bf(acci[fm][fn][r] + biv);
            }
        }
}

// ---- K2: fused score+softmax+PV. grid (S/128, 64), 256 thr (4 waves) ----
// Pass A: sum_t exp(|sim|/sqrt(2C)) per row (score recomputable, no max needed:
// mag >= 0 and bounded ~22 -> exp safe in fp32; softmax shift-invariant).
// Pass B: recompute scores, P = exp*inv, write normalized attn (mandatory),
// stage P bf16 -> LDS (overlaying K after barrier), PV MFMA -> av bf16.
template<int ST>
__global__ __launch_bounds__(256) void attn_fused_k(
    const unsigned short* __restrict__ qkv, float* __restrict__ attn,
    unsigned short* __restrict__ avb)
{
    const int bh = blockIdx.y;
    const int r0 = blockIdx.x * 128;
    const size_t poff = (size_t)bh * Sn * Cn;
    const unsigned short* qr = qkv + poff;
    const unsigned short* qi = qkv + Qsz + poff;
    const unsigned short* kr = qkv + 2 * Qsz + poff;
    const unsigned short* ki = qkv + 3 * Qsz + poff;
    const unsigned short* vr = qkv + 4 * Qsz + poff;
    const unsigned short* vi = qkv + 5 * Qsz + poff;

    __shared__ short Qr[128][68], Qi[128][68];   // 34 KB, resident
    __shared__ short KP[2][64][68];              // 17 KB: K tile, then P overlays
    __shared__ short Vtr[64][68], Vti[64][68];   // 17 KB: V^T [c][t]
    short (*Ps)[68] = (short(*)[68])KP;          // P [128][68] == KP memory

    const int tid = threadIdx.x;
    const int lane = tid & 63, wid = tid >> 6;
    const int lrow = lane & 15, g = lane >> 4, lk = g * 8;
    const int srow0 = 32 * wid;                  // score-phase: wave owns 32 rows
    const int wr = wid >> 1, wn = wid & 1;       // PV-phase 2x2

    // stage Q once: 128 rows x 64, 2 thr/row
    {
        const int row = tid >> 1, seg = (tid & 1) * 32;
        const unsigned short* pr = qr + (size_t)(r0 + row) * Cn + seg;
        const unsigned short* pi = qi + (size_t)(r0 + row) * Cn + seg;
        #pragma unroll
        for (int q = 0; q < 4; ++q) {
            *(short8v*)&Qr[row][seg + 8*q] = *(const short8v*)(pr + 8*q);
            *(short8v*)&Qi[row][seg + 8*q] = *(const short8v*)(pi + 8*q);
        }
    }
    const int kst_row = tid >> 2, kst_seg = (tid & 3) * 16;  // K stage: 4 thr/row
    const int vst_t = tid & 63, vst_c = (tid >> 6) * 16;     // V stage: 1 thr/t-row

    float ssum[2][4] = {};
    __syncthreads();  // Q ready

    // ---------- PASS A ----------
    for (int t0 = 0; t0 < Sn; t0 += 64) {
        short8v k_r0 = *(const short8v*)(kr + (size_t)(t0 + kst_row) * Cn + kst_seg);
        short8v k_r1 = *(const short8v*)(kr + (size_t)(t0 + kst_row) * Cn + kst_seg + 8);
        short8v k_i0 = *(const short8v*)(ki + (size_t)(t0 + kst_row) * Cn + kst_seg);
        short8v k_i1 = *(const short8v*)(ki + (size_t)(t0 + kst_row) * Cn + kst_seg + 8);
        __syncthreads();
        *(short8v*)&KP[0][kst_row][kst_seg]     = k_r0;
        *(short8v*)&KP[0][kst_row][kst_seg + 8] = k_r1;
        *(short8v*)&KP[1][kst_row][kst_seg]     = k_i0;
        *(short8v*)&KP[1][kst_row][kst_seg + 8] = k_i1;
        __syncthreads();

        f32x4 cr[2][4], ci[2][4];
        const f32x4 z4 = {0.f, 0.f, 0.f, 0.f};
        #pragma unroll
        for (int fm = 0; fm < 2; ++fm)
            #pragma unroll
            for (int fn = 0; fn < 4; ++fn) { cr[fm][fn] = z4; ci[fm][fn] = z4; }
        #pragma unroll
        for (int kh = 0; kh < 2; ++kh) {
            const int kof = kh*32 + lk;
            short8v br_[4], bi_[4];
            #pragma unroll
            for (int fn = 0; fn < 4; ++fn) {
                br_[fn] = *(const short8v*)&KP[0][fn*16 + lrow][kof];
                bi_[fn] = *(const short8v*)&KP[1][fn*16 + lrow][kof];
            }
            #pragma unroll
            for (int fm = 0; fm < 2; ++fm) {
                short8v ar = *(const short8v*)&Qr[srow0 + fm*16 + lrow][kof];
                short8v ai = *(const short8v*)&Qi[srow0 + fm*16 + lrow][kof];
                short8v ax = neg8(ar);
                #pragma unroll
                for (int fn = 0; fn < 4; ++fn) {
                    cr[fm][fn] = __builtin_amdgcn_mfma_f32_16x16x32_bf16(ar, br_[fn], cr[fm][fn], 0,0,0);
                    cr[fm][fn] = __builtin_amdgcn_mfma_f32_16x16x32_bf16(ai, bi_[fn], cr[fm][fn], 0,0,0);
                    ci[fm][fn] = __builtin_amdgcn_mfma_f32_16x16x32_bf16(ai, br_[fn], ci[fm][fn], 0,0,0);
                    ci[fm][fn] = __builtin_amdgcn_mfma_f32_16x16x32_bf16(ax, bi_[fn], ci[fm][fn], 0,0,0);
                }
            }
        }
        #pragma unroll
        for (int fm = 0; fm < 2; ++fm)
            #pragma unroll
            for (int rr = 0; rr < 4; ++rr) {
                float acc = 0.f;
                #pragma unroll
                for (int fn = 0; fn < 4; ++fn) {
                    const float re = cr[fm][fn][rr], im = ci[fm][fn][rr];
                    acc += __expf(sqrtf(fmaf(re, re, im*im)) * RDIV);
                }
                ssum[fm][rr] += acc;
            }
    }
    // row-sum reduce over the 16 lanes of each row group (g preserved)
    float inv[2][4];
    #pragma unroll
    for (int fm = 0; fm < 2; ++fm)
        #pragma unroll
        for (int rr = 0; rr < 4; ++rr) {
            float s = ssum[fm][rr];
            s += __shfl_xor(s, 1); s += __shfl_xor(s, 2);
            s += __shfl_xor(s, 4); s += __shfl_xor(s, 8);
            inv[fm][rr] = 1.f / s;
        }

    f32x4 pvr[4][2], pvi[4][2];
    const f32x4 z4 = {0.f, 0.f, 0.f, 0.f};
    #pragma unroll
    for (int fm = 0; fm < 4; ++fm)
        #pragma unroll
        for (int fn = 0; fn < 2; ++fn) { pvr[fm][fn] = z4; pvi[fm][fn] = z4; }

    // ---------- PASS B ----------
    for (int t0 = 0; t0 < Sn; t0 += 64) {
        short8v k_r0 = *(const short8v*)(kr + (size_t)(t0 + kst_row) * Cn + kst_seg);
        short8v k_r1 = *(const short8v*)(kr + (size_t)(t0 + kst_row) * Cn + kst_seg + 8);
        short8v k_i0 = *(const short8v*)(ki + (size_t)(t0 + kst_row) * Cn + kst_seg);
        short8v k_i1 = *(const short8v*)(ki + (size_t)(t0 + kst_row) * Cn + kst_seg + 8);
        short8v v_r0 = *(const short8v*)(vr + (size_t)(t0 + vst_t) * Cn + vst_c);
        short8v v_r1 = *(const short8v*)(vr + (size_t)(t0 + vst_t) * Cn + vst_c + 8);
        short8v v_i0 = *(const short8v*)(vi + (size_t)(t0 + vst_t) * Cn + vst_c);
        short8v v_i1 = *(const short8v*)(vi + (size_t)(t0 + vst_t) * Cn + vst_c + 8);
        __syncthreads();  // prev PV reads done
        *(short8v*)&KP[0][kst_row][kst_seg]     = k_r0;
        *(short8v*)&KP[0][kst_row][kst_seg + 8] = k_r1;
        *(short8v*)&KP[1][kst_row][kst_seg]     = k_i0;
        *(short8v*)&KP[1][kst_row][kst_seg + 8] = k_i1;
        #pragma unroll
        for (int j = 0; j < 8; ++j) {
            Vtr[vst_c + j][vst_t] = v_r0[j];
            Vtr[vst_c + 8 + j][vst_t] = v_r1[j];
            Vti[vst_c + j][vst_t] = v_i0[j];
            Vti[vst_c + 8 + j][vst_t] = v_i1[j];
        }
        __syncthreads();

        f32x4 cr[2][4], ci[2][4];
        #pragma unroll
        for (int fm = 0; fm < 2; ++fm)
            #pragma unroll
            for (int fn = 0; fn < 4; ++fn) { cr[fm][fn] = z4; ci[fm][fn] = z4; }
        #pragma unroll
        for (int kh = 0; kh < 2; ++kh) {
            const int kof = kh*32 + lk;
            short8v br_[4], bi_[4];
            #pragma unroll
            for (int fn = 0; fn < 4; ++fn) {
                br_[fn] = *(const short8v*)&KP[0][fn*16 + lrow][kof];
                bi_[fn] = *(const short8v*)&KP[1][fn*16 + lrow][kof];
            }
            #pragma unroll
            for (int fm = 0; fm < 2; ++fm) {
                short8v ar = *(const short8v*)&Qr[srow0 + fm*16 + lrow][kof];
                short8v ai = *(const short8v*)&Qi[srow0 + fm*16 + lrow][kof];
                short8v ax = neg8(ar);
                #pragma unroll
                for (int fn = 0; fn < 4; ++fn) {
                    cr[fm][fn] = __builtin_amdgcn_mfma_f32_16x16x32_bf16(ar, br_[fn], cr[fm][fn], 0,0,0);
                    cr[fm][fn] = __builtin_amdgcn_mfma_f32_16x16x32_bf16(ai, bi_[fn], cr[fm][fn], 0,0,0);
                    ci[fm][fn] = __builtin_amdgcn_mfma_f32_16x16x32_bf16(ai, br_[fn], ci[fm][fn], 0,0,0);
                    ci[fm][fn] = __builtin_amdgcn_mfma_f32_16x16x32_bf16(ax, bi_[fn], ci[fm][fn], 0,0,0);
                }
            }
        }
        // normalized P: write attn + stash values (K still being read by others)
        float pval[2][4][4];
        #pragma unroll
        for (int fm = 0; fm < 2; ++fm)
            #pragma unroll
            for (int fn = 0; fn < 4; ++fn) {
                const int t = t0 + fn*16 + lrow;
                #pragma unroll
                for (int rr = 0; rr < 4; ++rr) {
                    const float re = cr[fm][fn][rr], im = ci[fm][fn][rr];
                    const float p = __expf(sqrtf(fmaf(re, re, im*im)) * RDIV) * inv[fm][rr];
                    pval[fm][fn][rr] = p;
                    const size_t row = (size_t)bh * Sn + r0 + srow0 + fm*16 + g*4 + rr;
                    const size_t idx = (row * Sn + t) * (size_t)ST;
                    if (ST == 2) *(float2*)&attn[idx] = make_float2(p, 0.f);
                    else         attn[idx] = p;
                }
            }
        __syncthreads();  // all waves done reading K -> safe to overlay with P
        #pragma unroll
        for (int fm = 0; fm < 2; ++fm)
            #pragma unroll
            for (int fn = 0; fn < 4; ++fn)
                #pragma unroll
                for (int rr = 0; rr < 4; ++rr)
                    Ps[srow0 + fm*16 + g*4 + rr][fn*16 + lrow] = f2bf(pval[fm][fn][rr]);
        __syncthreads();  // P + V ready

        #pragma unroll
        for (int kh = 0; kh < 2; ++kh) {
            const int kof = kh*32 + lk;
            short8v bR[2], bI[2];
            #pragma unroll
            for (int fn = 0; fn < 2; ++fn) {
                bR[fn] = *(const short8v*)&Vtr[wn*32 + fn*16 + lrow][kof];
                bI[fn] = *(const short8v*)&Vti[wn*32 + fn*16 + lrow][kof];
            }
            #pragma unroll
            for (int fm = 0; fm < 4; ++fm) {
                short8v pA = *(const short8v*)&Ps[wr*64 + fm*16 + lrow][kof];
                #pragma unroll
                for (int fn = 0; fn < 2; ++fn) {
                    pvr[fm][fn] = __builtin_amdgcn_mfma_f32_16x16x32_bf16(pA, bR[fn], pvr[fm][fn], 0,0,0);
                    pvi[fm][fn] = __builtin_amdgcn_mfma_f32_16x16x32_bf16(pA, bI[fn], pvi[fm][fn], 0,0,0);
                }
            }
        }
    }

    // epilogue: av bf16 planar (B,S,E); av_i = -acc_i (conj V)
    const int b = bh >> 3, h = bh & 7;
    #pragma unroll
    for (int fm = 0; fm < 4; ++fm)
        #pragma unroll
        for (int fn = 0; fn < 2; ++fn) {
            const int c = wn*32 + fn*16 + lrow;
            #pragma unroll
            for (int rr = 0; rr < 4; ++rr) {
                const int row = r0 + wr*64 + fm*16 + g*4 + rr;
                const size_t addr = ((size_t)(b * Sn + row)) * En + h * Cn + c;
                avb[addr]       = f2bf( pvr[fm][fn][rr]);
                avb[Qsz + addr] = f2bf(-pvi[fm][fn][rr]);
            }
        }
}

// ---- K3: out = av(bf16) x wo^T + bo (MFMA). grid (M/128, F/64) ----
template<int ST>
__global__ __launch_bounds__(256) void out_proj_k(
    const unsigned short* __restrict__ avr, const unsigned short* __restrict__ avi,
    const float* __restrict__ wor, const float* __restrict__ woi,
    const float* __restrict__ bor, const float* __restrict__ boi,
    float* __restrict__ out)
{
    const int m0 = blockIdx.x * 128, n0 = blockIdx.y * 64;
    f32x4 accr[4][2], acci[4][2];
    const f32x4 z4 = {0.f, 0.f, 0.f, 0.f};
    #pragma unroll
    for (int fm = 0; fm < 4; ++fm)
        #pragma unroll
        for (int fn = 0; fn < 2; ++fn) { accr[fm][fn] = z4; acci[fm][fn] = z4; }

    cgemm_mfma_abf16<false>(avr, avi, m0, En, wor, woi, n0, En, En, accr, acci);

    const int lane = threadIdx.x & 63, wid = threadIdx.x >> 6;
    const int wr2 = wid >> 1, wn2 = wid & 1;
    #pragma unroll
    for (int fm = 0; fm < 4; ++fm)
        #pragma unroll
        for (int fn = 0; fn < 2; ++fn) {
            const int f = n0 + wn2*32 + fn*16 + (lane & 15);
            const float brv = bor[f], biv = boi[f];
            #pragma unroll
            for (int r = 0; r < 4; ++r) {
                const int m = m0 + wr2*64 + fm*16 + (lane >> 4)*4 + r;
                const size_t idx = ((size_t)m * Fn + f) * (size_t)ST;
                if (ST == 2)
                    *(float2*)&out[idx] = make_float2(accr[fm][fn][r] + brv, acci[fm][fn][r] + biv);
                else
                    out[idx] = accr[fm][fn][r] + brv;
            }
        }
}

template<int ST>
static void launch_all(const float* xr, const float* xi,
                       const float* wqr, const float* wqi, const float* bqr, const float* bqi,
                       const float* wkr, const float* wki, const float* bkr, const float* bki,
                       const float* wvr, const float* wvi, const float* bvr, const float* bvi,
                       const float* wor, const float* woi, const float* bor, const float* boi,
                       unsigned short* qkv, unsigned short* avb, float* out, hipStream_t stream)
{
    float* attn = out + OUT1 * ST;
    qkv_proj_k<<<dim3(Mn/128, En/64, 3), 256, 0, stream>>>(
        xr, xi, wqr, wqi, bqr, bqi, wkr, wki, bkr, bki, wvr, wvi, bvr, bvi, qkv);
    attn_fused_k<ST><<<dim3(Sn/128, Bn*Hn), 256, 0, stream>>>(qkv, attn, avb);
    out_proj_k<ST><<<dim3(Mn/128, Fn/64), 256, 0, stream>>>(
        avb, avb + Qsz, wor, woi, bor, boi, out);
}

extern "C" void kernel_launch(void* const* d_in, const int* in_sizes, int n_in,
                              void* d_out, int out_size, void* d_ws, size_t ws_size,
                              hipStream_t stream)
{
    // ---- host-side guards ----
    bool sizes_ok = (n_in == 18);
    if (sizes_ok) {
        sizes_ok = in_sizes[0] == XLIM && in_sizes[1] == XLIM;
        for (int g = 0; g < 3 && sizes_ok; ++g) {
            sizes_ok = in_sizes[2 + 4*g] == WLIM && in_sizes[3 + 4*g] == WLIM &&
                       in_sizes[4 + 4*g] == En  && in_sizes[5 + 4*g] == En;
        }
        sizes_ok = sizes_ok && in_sizes[14] == WLIM && in_sizes[15] == WLIM &&
                   in_sizes[16] == Fn && in_sizes[17] == Fn;
    }
    // ws: 8 bf16 planes of Qsz (q_r,q_i,k_r,k_i,v_r,v_i,av_r,av_i) = 64 MiB
    const size_t ws_needed = 8 * Qsz * sizeof(unsigned short);
    const bool ws_ok = (d_ws != nullptr) && (ws_size >= ws_needed);

    const long long fullF = 2LL * (long long)(OUT1 + ATT1);  // 142,606,336 floats
    const long long realF = (long long)(OUT1 + ATT1);        //  71,303,168 floats
    const int st = ((long long)out_size == fullF) ? 2
                 : ((long long)out_size == realF) ? 1 : 0;

    if (!sizes_ok || !ws_ok || st == 0) {
        float diag = !sizes_ok ? 3.0e9f
                   : !ws_ok    ? (float)(double)ws_size
                               : (float)out_size;
        diag_k<<<1, 1, 0, stream>>>((float*)d_out, diag);
        return;
    }

    const float* xr  = (const float*)d_in[0];
    const float* xi  = (const float*)d_in[1];
    const float* wqr = (const float*)d_in[2];
    const float* wqi = (const float*)d_in[3];
    const float* bqr = (const float*)d_in[4];
    const float* bqi = (const float*)d_in[5];
    const float* wkr = (const float*)d_in[6];
    const float* wki = (const float*)d_in[7];
    const float* bkr = (const float*)d_in[8];
    const float* bki = (const float*)d_in[9];
    const float* wvr = (const float*)d_in[10];
    const float* wvi = (const float*)d_in[11];
    const float* bvr = (const float*)d_in[12];
    const float* bvi = (const float*)d_in[13];
    const float* wor = (const float*)d_in[14];
    const float* woi = (const float*)d_in[15];
    const float* bor = (const float*)d_in[16];
    const float* boi = (const float*)d_in[17];

    unsigned short* qkv = (unsigned short*)d_ws;
    unsigned short* avb = qkv + 6 * Qsz;   // planes 6,7
    float* out = (float*)d_out;

    if (st == 2)
        launch_all<2>(xr, xi, wqr, wqi, bqr, bqi, wkr, wki, bkr, bki,
                      wvr, wvi, bvr, bvi, wor, woi, bor, boi, qkv, avb, out, stream);
    else
        launch_all<1>(xr, xi, wqr, wqi, bqr, bqi, wkr, wki, bkr, bki,
                      wvr, wvi, bvr, bvi, wor, woi, bor, boi, qkv, avb, out, stream);
}